// Round 7
// baseline (985.121 us; speedup 1.0000x reference)
//
#include <hip/hip_runtime.h>
#include <hip/hip_bf16.h>
#include <math.h>

#define B_ 4
#define T_ 1024
#define D_ 1024
#define H_ 16
#define DH_ 64
#define F_ 4096
#define E_ 8
#define NTOK 4096
#define EPS_ 1e-5f

typedef float f32x4 __attribute__((ext_vector_type(4)));
typedef __bf16 bf16x8 __attribute__((ext_vector_type(8)));
typedef _Float16 f16x8 __attribute__((ext_vector_type(8)));

__device__ __forceinline__ unsigned short f2bf(float f) {
    unsigned u = __float_as_uint(f);
    u = u + 0x7fffu + ((u >> 16) & 1u);   // round-to-nearest-even
    return (unsigned short)(u >> 16);
}

// split fp32 into fp16 hi + fp16 lo where x ~= hi + lo/2048 (rel err ~2^-22)
__device__ __forceinline__ void splitf(float x, unsigned short& h, unsigned short& l) {
    _Float16 hf = (_Float16)x;
    _Float16 lf = (_Float16)((x - (float)hf) * 2048.0f);
    h = __builtin_bit_cast(unsigned short, hf);
    l = __builtin_bit_cast(unsigned short, lf);
}

// Abramowitz-Stegun 7.1.26 erf, |err| < 1.5e-7 (invisible after bf16 round)
__device__ __forceinline__ float erf_fast(float x) {
    float ax = fabsf(x);
    float t = 1.0f / fmaf(0.3275911f, ax, 1.0f);
    float y = t * fmaf(t, fmaf(t, fmaf(t, fmaf(t, 1.061405429f, -1.453152027f),
                  1.421413741f), -0.284496736f), 0.254829592f);
    float r = 1.0f - y * __expf(-ax * ax);
    return copysignf(r, x);
}

// async global->LDS, 16B per lane; LDS dest = wave-uniform base + lane*16
__device__ __forceinline__ void gload16(const unsigned short* g, unsigned short* l) {
    __builtin_amdgcn_global_load_lds(
        (const __attribute__((address_space(1))) unsigned int*)g,
        (__attribute__((address_space(3))) unsigned int*)l,
        16, 0, 0);
}

__device__ __forceinline__ void blockreduce2(float& s, float& sq) {
    #pragma unroll
    for (int o = 32; o > 0; o >>= 1) { s += __shfl_xor(s, o); sq += __shfl_xor(sq, o); }
    __shared__ float ls[4], lq[4];
    int w = threadIdx.x >> 6;
    if ((threadIdx.x & 63) == 0) { ls[w] = s; lq[w] = sq; }
    __syncthreads();
    s = ls[0] + ls[1] + ls[2] + ls[3];
    sq = lq[0] + lq[1] + lq[2] + lq[3];
}

// ---------------- zero routing counters ----------------
__global__ void k_zero(int* __restrict__ cnt) {
    if (threadIdx.x < E_) cnt[threadIdx.x] = 0;
}

// ------------- transpose fp32[e][R][C] -> bf16[e][C][R] -------------
__global__ void k_tconv(const float* __restrict__ in, unsigned short* __restrict__ out,
                        int R, int C) {
    __shared__ float tile[32][33];
    int e = blockIdx.z;
    const float* ine = in + (size_t)e * R * C;
    unsigned short* oute = out + (size_t)e * R * C;
    int tx = threadIdx.x & 31, ty = threadIdx.x >> 5;   // 32 x 8
    int c0 = blockIdx.x * 32, r0 = blockIdx.y * 32;
    #pragma unroll
    for (int j = 0; j < 32; j += 8)
        tile[ty + j][tx] = ine[(size_t)(r0 + ty + j) * C + c0 + tx];
    __syncthreads();
    #pragma unroll
    for (int j = 0; j < 32; j += 8)
        oute[(size_t)(c0 + ty + j) * R + r0 + tx] = f2bf(tile[tx][ty + j]);
}

// ------- transpose 4 attn weights fp32[D][D] -> split fp16 [z][N][K] -------
__global__ void k_tconv_split(const float* __restrict__ w0, const float* __restrict__ w1,
        const float* __restrict__ w2, const float* __restrict__ w3,
        unsigned short* __restrict__ ohi, unsigned short* __restrict__ olo) {
    __shared__ float tile[32][33];
    int z = blockIdx.z;
    const float* in = (z == 0) ? w0 : ((z == 1) ? w1 : ((z == 2) ? w2 : w3));
    unsigned short* oh = ohi + (size_t)z * D_ * D_;
    unsigned short* ol = olo + (size_t)z * D_ * D_;
    int tx = threadIdx.x & 31, ty = threadIdx.x >> 5;   // 32 x 8
    int c0 = blockIdx.x * 32, r0 = blockIdx.y * 32;
    #pragma unroll
    for (int j = 0; j < 32; j += 8)
        tile[ty + j][tx] = in[(size_t)(r0 + ty + j) * D_ + c0 + tx];
    __syncthreads();
    #pragma unroll
    for (int j = 0; j < 32; j += 8) {
        unsigned short h, l;
        splitf(tile[tx][ty + j], h, l);
        size_t o = (size_t)(c0 + ty + j) * D_ + r0 + tx;
        oh[o] = h; ol[o] = l;
    }
}

// ---------------- LayerNorm 1 (split fp16 out) ----------------
__global__ void k_ln1(const float* __restrict__ x, const float* __restrict__ g,
                      const float* __restrict__ b, unsigned short* __restrict__ hh,
                      unsigned short* __restrict__ hl) {
    int row = blockIdx.x, t = threadIdx.x;
    f32x4 v = *(const f32x4*)(x + (size_t)row * D_ + t * 4);
    float s = v.x + v.y + v.z + v.w;
    float sq = v.x * v.x + v.y * v.y + v.z * v.z + v.w * v.w;
    blockreduce2(s, sq);
    float mean = s * (1.0f / D_);
    float var = sq * (1.0f / D_) - mean * mean;
    float inv = rsqrtf(var + EPS_);
    f32x4 gv = *(const f32x4*)(g + t * 4);
    f32x4 bv = *(const f32x4*)(b + t * 4);
    ushort4 oh, ol;
    float o0 = (v.x - mean) * inv * gv.x + bv.x;
    float o1 = (v.y - mean) * inv * gv.y + bv.y;
    float o2 = (v.z - mean) * inv * gv.z + bv.z;
    float o3 = (v.w - mean) * inv * gv.w + bv.w;
    splitf(o0, oh.x, ol.x); splitf(o1, oh.y, ol.y);
    splitf(o2, oh.z, ol.z); splitf(o3, oh.w, ol.w);
    *(ushort4*)(hh + (size_t)row * D_ + t * 4) = oh;
    *(ushort4*)(hl + (size_t)row * D_ + t * 4) = ol;
}

// ------- split-fp16 3-pass MFMA 128x128 GEMM core (fp32-equivalent) -------
// result = acc1 + acc2 * (1/2048)
#define LDK2 40
__device__ __forceinline__ void mfma_split(const unsigned short* __restrict__ Ah,
        const unsigned short* __restrict__ Al, int strideA, int m0,
        const unsigned short* __restrict__ Bh, const unsigned short* __restrict__ Bl,
        int strideB, int n0, int K, f32x4 acc1[4][4], f32x4 acc2[4][4]) {
    __shared__ unsigned short AsH[128 * LDK2];
    __shared__ unsigned short AsL[128 * LDK2];
    __shared__ unsigned short BsH[128 * LDK2];
    __shared__ unsigned short BsL[128 * LDK2];
    int t = threadIdx.x;
    int lane = t & 63, w = t >> 6;
    int wm = (w >> 1) * 64, wn = (w & 1) * 64;
    int r = t >> 1, kc = (t & 1) * 16;
    const unsigned short* pAh = Ah + (size_t)(m0 + r) * strideA + kc;
    const unsigned short* pAl = Al + (size_t)(m0 + r) * strideA + kc;
    const unsigned short* pBh = Bh + (size_t)(n0 + r) * strideB + kc;
    const unsigned short* pBl = Bl + (size_t)(n0 + r) * strideB + kc;
    int c15 = lane & 15, fk = (lane >> 4) * 8;
    unsigned short* wAh = &AsH[r * LDK2 + kc];
    unsigned short* wAl = &AsL[r * LDK2 + kc];
    unsigned short* wBh = &BsH[r * LDK2 + kc];
    unsigned short* wBl = &BsL[r * LDK2 + kc];
    uint4 ah0 = *(const uint4*)(pAh);
    uint4 ah1 = *(const uint4*)(pAh + 8);
    uint4 al0 = *(const uint4*)(pAl);
    uint4 al1 = *(const uint4*)(pAl + 8);
    uint4 bh0 = *(const uint4*)(pBh);
    uint4 bh1 = *(const uint4*)(pBh + 8);
    uint4 bl0 = *(const uint4*)(pBl);
    uint4 bl1 = *(const uint4*)(pBl + 8);
    for (int k0 = 0; k0 < K; k0 += 32) {
        __syncthreads();
        *(uint4*)(wAh) = ah0; *(uint4*)(wAh + 8) = ah1;
        *(uint4*)(wAl) = al0; *(uint4*)(wAl + 8) = al1;
        *(uint4*)(wBh) = bh0; *(uint4*)(wBh + 8) = bh1;
        *(uint4*)(wBl) = bl0; *(uint4*)(wBl + 8) = bl1;
        __syncthreads();
        if (k0 + 32 < K) {
            ah0 = *(const uint4*)(pAh + k0 + 32);
            ah1 = *(const uint4*)(pAh + k0 + 40);
            al0 = *(const uint4*)(pAl + k0 + 32);
            al1 = *(const uint4*)(pAl + k0 + 40);
            bh0 = *(const uint4*)(pBh + k0 + 32);
            bh1 = *(const uint4*)(pBh + k0 + 40);
            bl0 = *(const uint4*)(pBl + k0 + 32);
            bl1 = *(const uint4*)(pBl + k0 + 40);
        }
        f16x8 bfh[4], bfl[4];
        #pragma unroll
        for (int i = 0; i < 4; i++) {
            bfh[i] = *(const f16x8*)(&BsH[(wn + c15 + i * 16) * LDK2 + fk]);
            bfl[i] = *(const f16x8*)(&BsL[(wn + c15 + i * 16) * LDK2 + fk]);
        }
        #pragma unroll
        for (int mi = 0; mi < 4; mi++) {
            f16x8 afh = *(const f16x8*)(&AsH[(wm + c15 + mi * 16) * LDK2 + fk]);
            f16x8 afl = *(const f16x8*)(&AsL[(wm + c15 + mi * 16) * LDK2 + fk]);
            #pragma unroll
            for (int ni = 0; ni < 4; ni++) {
                acc1[mi][ni] = __builtin_amdgcn_mfma_f32_16x16x32_f16(afh, bfh[ni], acc1[mi][ni], 0, 0, 0);
                acc2[mi][ni] = __builtin_amdgcn_mfma_f32_16x16x32_f16(afh, bfl[ni], acc2[mi][ni], 0, 0, 0);
                acc2[mi][ni] = __builtin_amdgcn_mfma_f32_16x16x32_f16(afl, bfh[ni], acc2[mi][ni], 0, 0, 0);
            }
        }
    }
}

// -------- QKV projection (split-fp16 MFMA), scatter to split-fp16 [B,H,T,DH] --------
__global__ __launch_bounds__(256, 2) void k_qkv_split(
        const unsigned short* __restrict__ h1h, const unsigned short* __restrict__ h1l,
        const unsigned short* __restrict__ wth, const unsigned short* __restrict__ wtl,
        const float* __restrict__ bq, const float* __restrict__ bk, const float* __restrict__ bv,
        unsigned short* __restrict__ Qh, unsigned short* __restrict__ Ql,
        unsigned short* __restrict__ Kh, unsigned short* __restrict__ Kl,
        unsigned short* __restrict__ Vh, unsigned short* __restrict__ Vl) {
    int which = blockIdx.z;
    const unsigned short* Bh = wth + (size_t)which * D_ * D_;
    const unsigned short* Bl = wtl + (size_t)which * D_ * D_;
    const float* bias = (which == 0) ? bq : ((which == 1) ? bk : bv);
    unsigned short* Oh = (which == 0) ? Qh : ((which == 1) ? Kh : Vh);
    unsigned short* Ol = (which == 0) ? Ql : ((which == 1) ? Kl : Vl);
    f32x4 a1[4][4], a2[4][4];
    #pragma unroll
    for (int i = 0; i < 4; i++)
        #pragma unroll
        for (int j = 0; j < 4; j++) {
            a1[i][j].x = 0.f; a1[i][j].y = 0.f; a1[i][j].z = 0.f; a1[i][j].w = 0.f;
            a2[i][j].x = 0.f; a2[i][j].y = 0.f; a2[i][j].z = 0.f; a2[i][j].w = 0.f;
        }
    int m0 = blockIdx.y * 128, n0 = blockIdx.x * 128;
    mfma_split(h1h, h1l, D_, m0, Bh, Bl, D_, n0, D_, a1, a2);
    int lane = threadIdx.x & 63, w = threadIdx.x >> 6;
    int wm = (w >> 1) * 64, wn = (w & 1) * 64;
    int c15 = lane & 15, quad = lane >> 4;
    #pragma unroll
    for (int mi = 0; mi < 4; mi++) {
        #pragma unroll
        for (int rr = 0; rr < 4; rr++) {
            int row = m0 + wm + mi * 16 + quad * 4 + rr;
            int bidx = row >> 10, tt = row & 1023;
            #pragma unroll
            for (int ni = 0; ni < 4; ni++) {
                int col = n0 + wn + ni * 16 + c15;
                float vv = a1[mi][ni][rr] + a2[mi][ni][rr] * (1.0f / 2048.0f) + bias[col];
                unsigned short hs, ls;
                splitf(vv, hs, ls);
                size_t idx = (((size_t)bidx * H_ + (col >> 6)) * T_ + tt) * DH_ + (col & 63);
                Oh[idx] = hs; Ol[idx] = ls;
            }
        }
    }
}

// -------- output projection, split-K=2: partial GEMM only (bias+residual in ln2_gate) --------
__global__ __launch_bounds__(256, 2) void k_proj_split(
        const unsigned short* __restrict__ ah, const unsigned short* __restrict__ al,
        const unsigned short* __restrict__ wh, const unsigned short* __restrict__ wl,
        float* __restrict__ xp) {
    int ks = blockIdx.z;              // K half: cols ks*512 .. +512
    f32x4 a1[4][4], a2[4][4];
    #pragma unroll
    for (int i = 0; i < 4; i++)
        #pragma unroll
        for (int j = 0; j < 4; j++) {
            a1[i][j].x = 0.f; a1[i][j].y = 0.f; a1[i][j].z = 0.f; a1[i][j].w = 0.f;
            a2[i][j].x = 0.f; a2[i][j].y = 0.f; a2[i][j].z = 0.f; a2[i][j].w = 0.f;
        }
    int m0 = blockIdx.y * 128, n0 = blockIdx.x * 128;
    mfma_split(ah + ks * 512, al + ks * 512, D_, m0,
               wh + ks * 512, wl + ks * 512, D_, n0, 512, a1, a2);
    float* dst = xp + (size_t)ks * NTOK * D_;
    int lane = threadIdx.x & 63, w = threadIdx.x >> 6;
    int wm = (w >> 1) * 64, wn = (w & 1) * 64;
    int c15 = lane & 15, quad = lane >> 4;
    #pragma unroll
    for (int mi = 0; mi < 4; mi++) {
        #pragma unroll
        for (int rr = 0; rr < 4; rr++) {
            int row = m0 + wm + mi * 16 + quad * 4 + rr;
            #pragma unroll
            for (int ni = 0; ni < 4; ni++) {
                int col = n0 + wn + ni * 16 + c15;
                dst[(size_t)row * D_ + col] = a1[mi][ni][rr] + a2[mi][ni][rr] * (1.0f / 2048.0f);
            }
        }
    }
}

// ---------------- flash attention pass 1: split-fp16 MFMA ----------------
#define NSLOT 40
__device__ __forceinline__ int slot_base(int qt) {
    const int base[16] = {0,1,2,3,4,6,8,10,12,15,18,21,24,28,32,36};
    return base[qt];
}
// swizzled byte offset into a [64][64] ushort LDS tile (row stride 128B)
__device__ __forceinline__ int swzb(int r, int cb) {
    return r * 128 + (cb ^ ((r & 7) << 4));
}
__global__ __launch_bounds__(256, 3) void k_attn1(
        const unsigned short* __restrict__ Qh, const unsigned short* __restrict__ Ql,
        const unsigned short* __restrict__ Kh, const unsigned short* __restrict__ Kl,
        const unsigned short* __restrict__ Vh, const unsigned short* __restrict__ Vl,
        float* __restrict__ opart, float* __restrict__ mlpart) {
    __shared__ unsigned short KsH[64 * 64], KsL[64 * 64];
    __shared__ unsigned short VtH[64 * 64], VtL[64 * 64];   // [d][k]
    __shared__ unsigned short PsH[64 * 64], PsL[64 * 64];   // [q][k]
    int sp = blockIdx.x, qt = blockIdx.y, bh = blockIdx.z;
    int lim = (qt + 1) * 64;
    int s0 = sp * 256;
    if (s0 >= lim) return;
    int ntile = min(4, (lim - s0) >> 6);
    int t = threadIdx.x;
    int lane = t & 63, w = t >> 6;
    int c15 = lane & 15, quad = lane >> 4;
    size_t bho = (size_t)bh * T_ * DH_;
    // ---- Q fragments directly to registers (reused across all k-tiles) ----
    f16x8 qfh[2], qfl[2];
    {
        const unsigned short* qb = Qh + bho + (size_t)(qt * 64 + w * 16 + c15) * DH_ + quad * 8;
        const unsigned short* ql2 = Ql + bho + (size_t)(qt * 64 + w * 16 + c15) * DH_ + quad * 8;
        qfh[0] = *(const f16x8*)(qb);
        qfh[1] = *(const f16x8*)(qb + 32);
        qfl[0] = *(const f16x8*)(ql2);
        qfl[1] = *(const f16x8*)(ql2 + 32);
    }
    // ---- staging registers + loader (prefetch pattern) ----
    int kr = t >> 2, kcb = (t & 3) * 32;            // K: row kr, byte cols kcb, kcb+16
    int vkp = (t & 31) * 2, vd0 = (t >> 5) * 8;     // V: k pair (vkp,vkp+1), d range vd0..+8
    uint4 kh0, kh1, kl0, kl1, vh0, vh1, vl0, vl1;
    auto loadKV = [&](int kbase) {
        const unsigned short* sh = Kh + bho + (size_t)(kbase + kr) * DH_ + (kcb >> 1);
        const unsigned short* sl = Kl + bho + (size_t)(kbase + kr) * DH_ + (kcb >> 1);
        kh0 = *(const uint4*)(sh);     kh1 = *(const uint4*)(sh + 8);
        kl0 = *(const uint4*)(sl);     kl1 = *(const uint4*)(sl + 8);
        const unsigned short* vh = Vh + bho + (size_t)(kbase + vkp) * DH_ + vd0;
        const unsigned short* vl = Vl + bho + (size_t)(kbase + vkp) * DH_ + vd0;
        vh0 = *(const uint4*)(vh);     vh1 = *(const uint4*)(vh + DH_);
        vl0 = *(const uint4*)(vl);     vl1 = *(const uint4*)(vl + DH_);
    };
    loadKV(s0);
    f32x4 o1[4], o2[4];
    #pragma unroll
    for (int i = 0; i < 4; i++) {
        o1[i].x = 0.f; o1[i].y = 0.f; o1[i].z = 0.f; o1[i].w = 0.f;
        o2[i].x = 0.f; o2[i].y = 0.f; o2[i].z = 0.f; o2[i].w = 0.f;
    }
    float m[4] = {-1e30f, -1e30f, -1e30f, -1e30f};
    float l[4] = {0.f, 0.f, 0.f, 0.f};
    int qglob0 = qt * 64 + w * 16 + quad * 4;   // thread's first q row
    for (int kt = 0; kt < ntile; kt++) {
        int kbase = s0 + kt * 64;
        __syncthreads();   // prev-iter readers of Ks/Vt/Ps done
        // ---- write staged K (swizzled) ----
        *(uint4*)((char*)KsH + swzb(kr, kcb))      = kh0;
        *(uint4*)((char*)KsH + swzb(kr, kcb + 16)) = kh1;
        *(uint4*)((char*)KsL + swzb(kr, kcb))      = kl0;
        *(uint4*)((char*)KsL + swzb(kr, kcb + 16)) = kl1;
        // ---- write staged V transposed [d][k], paired b32 (conflict-free) ----
        {
            unsigned short h0a[8], h1a[8], l0a[8], l1a[8];
            *(uint4*)h0a = vh0; *(uint4*)h1a = vh1;
            *(uint4*)l0a = vl0; *(uint4*)l1a = vl1;
            #pragma unroll
            for (int i = 0; i < 8; i++) {
                int d = vd0 + i;
                unsigned hv32 = (unsigned)h0a[i] | ((unsigned)h1a[i] << 16);
                unsigned lv32 = (unsigned)l0a[i] | ((unsigned)l1a[i] << 16);
                *(unsigned*)((char*)VtH + swzb(d, vkp * 2)) = hv32;
                *(unsigned*)((char*)VtL + swzb(d, vkp * 2)) = lv32;
            }
        }
        __syncthreads();
        if (kt + 1 < ntile) loadKV(kbase + 64);   // prefetch: latency hides under compute
        // ---- QK^T: wave computes S[16q x 64k], split 3-pass ----
        f32x4 s1[4], s2[4];
        #pragma unroll
        for (int i = 0; i < 4; i++) {
            s1[i].x = 0.f; s1[i].y = 0.f; s1[i].z = 0.f; s1[i].w = 0.f;
            s2[i].x = 0.f; s2[i].y = 0.f; s2[i].z = 0.f; s2[i].w = 0.f;
        }
        #pragma unroll
        for (int kk = 0; kk < 2; kk++) {
            int cb = kk * 64 + quad * 16;
            f16x8 ah = qfh[kk];
            f16x8 al = qfl[kk];
            #pragma unroll
            for (int ni = 0; ni < 4; ni++) {
                f16x8 bh16 = *(const f16x8*)((char*)KsH + swzb(ni * 16 + c15, cb));
                f16x8 bl16 = *(const f16x8*)((char*)KsL + swzb(ni * 16 + c15, cb));
                s1[ni] = __builtin_amdgcn_mfma_f32_16x16x32_f16(ah, bh16, s1[ni], 0, 0, 0);
                s2[ni] = __builtin_amdgcn_mfma_f32_16x16x32_f16(ah, bl16, s2[ni], 0, 0, 0);
                s2[ni] = __builtin_amdgcn_mfma_f32_16x16x32_f16(al, bh16, s2[ni], 0, 0, 0);
            }
        }
        // ---- combine, scale, mask ----
        f32x4 p[4];
        #pragma unroll
        for (int ni = 0; ni < 4; ni++)
            p[ni] = s1[ni] * 0.125f + s2[ni] * 6.103515625e-5f;   // 0.125/2048
        #pragma unroll
        for (int ni = 0; ni < 4; ni++) {
            int kglob = kbase + c15 + 16 * ni;
            #pragma unroll
            for (int r = 0; r < 4; r++)
                p[ni][r] = (kglob <= qglob0 + r) ? p[ni][r] : -1e30f;
        }
        // ---- online softmax (per q row; row spans the 16 low lanes) ----
        float alpha[4];
        #pragma unroll
        for (int r = 0; r < 4; r++) {
            float rm = fmaxf(fmaxf(p[0][r], p[1][r]), fmaxf(p[2][r], p[3][r]));
            rm = fmaxf(rm, __shfl_xor(rm, 1));
            rm = fmaxf(rm, __shfl_xor(rm, 2));
            rm = fmaxf(rm, __shfl_xor(rm, 4));
            rm = fmaxf(rm, __shfl_xor(rm, 8));
            float mnew = fmaxf(m[r], rm);
            alpha[r] = __expf(m[r] - mnew);
            m[r] = mnew;
            float rs = 0.f;
            #pragma unroll
            for (int ni = 0; ni < 4; ni++) {
                float pv = (p[ni][r] > -1e29f) ? __expf(p[ni][r] - mnew) : 0.f;
                p[ni][r] = pv;
                rs += pv;
            }
            rs += __shfl_xor(rs, 1);
            rs += __shfl_xor(rs, 2);
            rs += __shfl_xor(rs, 4);
            rs += __shfl_xor(rs, 8);
            l[r] = l[r] * alpha[r] + rs;
        }
        #pragma unroll
        for (int ni = 0; ni < 4; ni++) {
            o1[ni].x *= alpha[0]; o1[ni].y *= alpha[1]; o1[ni].z *= alpha[2]; o1[ni].w *= alpha[3];
            o2[ni].x *= alpha[0]; o2[ni].y *= alpha[1]; o2[ni].z *= alpha[2]; o2[ni].w *= alpha[3];
        }
        // ---- write P split to LDS [q][k] ----
        #pragma unroll
        for (int ni = 0; ni < 4; ni++) {
            int cbyte = (c15 + 16 * ni) * 2;
            #pragma unroll
            for (int r = 0; r < 4; r++) {
                unsigned short hs, ls;
                splitf(p[ni][r], hs, ls);
                int row = w * 16 + quad * 4 + r;
                *(unsigned short*)((char*)PsH + swzb(row, cbyte)) = hs;
                *(unsigned short*)((char*)PsL + swzb(row, cbyte)) = ls;
            }
        }
        __syncthreads();
        // ---- PV: o[16q x 64d] += P @ V, split 3-pass ----
        #pragma unroll
        for (int kk = 0; kk < 2; kk++) {
            int cb = kk * 64 + quad * 16;
            f16x8 ph = *(const f16x8*)((char*)PsH + swzb(w * 16 + c15, cb));
            f16x8 pl = *(const f16x8*)((char*)PsL + swzb(w * 16 + c15, cb));
            #pragma unroll
            for (int ni = 0; ni < 4; ni++) {
                f16x8 vh16 = *(const f16x8*)((char*)VtH + swzb(ni * 16 + c15, cb));
                f16x8 vl16 = *(const f16x8*)((char*)VtL + swzb(ni * 16 + c15, cb));
                o1[ni] = __builtin_amdgcn_mfma_f32_16x16x32_f16(ph, vh16, o1[ni], 0, 0, 0);
                o2[ni] = __builtin_amdgcn_mfma_f32_16x16x32_f16(ph, vl16, o2[ni], 0, 0, 0);
                o2[ni] = __builtin_amdgcn_mfma_f32_16x16x32_f16(pl, vh16, o2[ni], 0, 0, 0);
            }
        }
    }
    // ---- write unnormalized partial + (m,l) ----
    int slot = bh * NSLOT + slot_base(qt) + sp;
    float* dst = opart + (size_t)slot * 64 * 64;
    #pragma unroll
    for (int ni = 0; ni < 4; ni++) {
        #pragma unroll
        for (int r = 0; r < 4; r++) {
            float val = o1[ni][r] + o2[ni][r] * (1.0f / 2048.0f);
            dst[(size_t)(w * 16 + quad * 4 + r) * 64 + c15 + 16 * ni] = val;
        }
    }
    if (c15 == 0) {
        #pragma unroll
        for (int r = 0; r < 4; r++) {
            int row = w * 16 + quad * 4 + r;
            mlpart[slot * 128 + row * 2 + 0] = m[r];
            mlpart[slot * 128 + row * 2 + 1] = l[r];
        }
    }
}

// ------- flash attention pass 2: merge partials, normalize, split-fp16 out -------
__global__ void k_attn2(const float* __restrict__ opart, const float* __restrict__ mlpart,
                        unsigned short* __restrict__ atth, unsigned short* __restrict__ attl) {
    int qt = blockIdx.x, bh = blockIdx.y;
    int b = bh >> 4, h = bh & 15;
    int nsp = (qt >> 2) + 1;
    int slot0 = bh * NSLOT + slot_base(qt);
    int tid = threadIdx.x;
    int q = tid >> 2, d0 = (tid & 3) * 16;
    float ms[4], ls[4];
    float mx = -1e30f;
    for (int s = 0; s < nsp; s++) {
        ms[s] = mlpart[(slot0 + s) * 128 + q * 2 + 0];
        ls[s] = mlpart[(slot0 + s) * 128 + q * 2 + 1];
        mx = fmaxf(mx, ms[s]);
    }
    float den = 0.f;
    f32x4 num[4];
    #pragma unroll
    for (int i = 0; i < 4; i++) { num[i].x = 0.f; num[i].y = 0.f; num[i].z = 0.f; num[i].w = 0.f; }
    for (int s = 0; s < nsp; s++) {
        float sc = __expf(ms[s] - mx);
        den += ls[s] * sc;
        const float* src = opart + ((size_t)(slot0 + s) * 64 + q) * 64 + d0;
        #pragma unroll
        for (int i = 0; i < 4; i++) num[i] += sc * *(const f32x4*)(src + i * 4);
    }
    float inv = 1.0f / den;
    size_t base = ((size_t)(b * T_ + qt * 64 + q)) * D_ + h * DH_ + d0;
    #pragma unroll
    for (int i = 0; i < 4; i++) {
        f32x4 v = num[i] * inv;
        ushort4 hh, ll;
        splitf(v.x, hh.x, ll.x); splitf(v.y, hh.y, ll.y);
        splitf(v.z, hh.z, ll.z); splitf(v.w, hh.w, ll.w);
        *(ushort4*)(atth + base + i * 4) = hh;
        *(ushort4*)(attl + base + i * 4) = ll;
    }
}

// ---- LN2 + gate: merge proj partials + bias + residual -> x2, then LN + top-2 ----
__global__ void k_ln2_gate(const float* __restrict__ xp, const float* __restrict__ bo,
        const float* __restrict__ xin, float* __restrict__ x2,
        const float* __restrict__ g, const float* __restrict__ bb,
        const float* __restrict__ gw, const float* __restrict__ gb,
        unsigned short* __restrict__ h2, int* __restrict__ cnt, int* __restrict__ lst,
        int* __restrict__ te, int* __restrict__ ts, float* __restrict__ tp) {
    int row = blockIdx.x, t = threadIdx.x;
    f32x4 v = *(const f32x4*)(xp + (size_t)row * D_ + t * 4)
            + *(const f32x4*)(xp + (size_t)NTOK * D_ + (size_t)row * D_ + t * 4)
            + *(const f32x4*)(bo + t * 4)
            + *(const f32x4*)(xin + (size_t)row * D_ + t * 4);
    *(f32x4*)(x2 + (size_t)row * D_ + t * 4) = v;
    float s = v.x + v.y + v.z + v.w;
    float sq = v.x * v.x + v.y * v.y + v.z * v.z + v.w * v.w;
    blockreduce2(s, sq);
    float mean = s * (1.0f / D_), var = sq * (1.0f / D_) - mean * mean;
    float inv = rsqrtf(var + EPS_);
    f32x4 gv = *(const f32x4*)(g + t * 4);
    f32x4 bv = *(const f32x4*)(bb + t * 4);
    float hv[4];
    #pragma unroll
    for (int i = 0; i < 4; i++) hv[i] = (v[i] - mean) * inv * gv[i] + bv[i];
    ushort4 hb;
    hb.x = f2bf(hv[0]); hb.y = f2bf(hv[1]); hb.z = f2bf(hv[2]); hb.w = f2bf(hv[3]);
    *(ushort4*)(&h2[(size_t)row * D_ + t * 4]) = hb;
    float lg[8];
    #pragma unroll
    for (int e2 = 0; e2 < 8; e2++) lg[e2] = 0.f;
    #pragma unroll
    for (int i = 0; i < 4; i++) {
        const float* gr = gw + (size_t)(t * 4 + i) * E_;
        f32x4 g0 = *(const f32x4*)(gr);
        f32x4 g1 = *(const f32x4*)(gr + 4);
        lg[0] = fmaf(hv[i], g0.x, lg[0]); lg[1] = fmaf(hv[i], g0.y, lg[1]);
        lg[2] = fmaf(hv[i], g0.z, lg[2]); lg[3] = fmaf(hv[i], g0.w, lg[3]);
        lg[4] = fmaf(hv[i], g1.x, lg[4]); lg[5] = fmaf(hv[i], g1.y, lg[5]);
        lg[6] = fmaf(hv[i], g1.z, lg[6]); lg[7] = fmaf(hv[i], g1.w, lg[7]);
    }
    #pragma unroll
    for (int o = 32; o > 0; o >>= 1) {
        #pragma unroll
        for (int e2 = 0; e2 < 8; e2++) lg[e2] += __shfl_xor(lg[e2], o);
    }
    __shared__ float lred[4][8];
    int w = t >> 6;
    if ((t & 63) == 0) {
        #pragma unroll
        for (int e2 = 0; e2 < 8; e2++) lred[w][e2] = lg[e2];
    }
    __syncthreads();
    if (t == 0) {
        float L[8];
        #pragma unroll
        for (int e2 = 0; e2 < 8; e2++)
            L[e2] = (lred[0][e2] + lred[1][e2] + lred[2][e2] + lred[3][e2] + gb[e2]) / 0.9f;
        int e0 = 0, e1 = -1; float v0 = L[0], v1 = -3e38f;
        #pragma unroll
        for (int e2 = 1; e2 < 8; e2++) {
            float xv = L[e2];
            if (xv > v0)      { v1 = v0; e1 = e0; v0 = xv; e0 = e2; }
            else if (xv > v1) { v1 = xv; e1 = e2; }
        }
        float ex = __expf(v1 - v0);
        float denom = 1.0f + ex;
        float p0 = 1.0f / denom, p1 = ex / denom;
        int s0 = atomicAdd(&cnt[e0], 1);
        int s1 = atomicAdd(&cnt[e1], 1);
        lst[e0 * NTOK + s0] = row;
        lst[e1 * NTOK + s1] = row;
        te[row * 2 + 0] = e0; te[row * 2 + 1] = e1;
        ts[row * 2 + 0] = s0; ts[row * 2 + 1] = s1;
        tp[row * 2 + 0] = p0; tp[row * 2 + 1] = p1;
    }
}

__global__ void k_offs(const int* __restrict__ cnt, int* __restrict__ offs) {
    if (threadIdx.x == 0 && blockIdx.x == 0) {
        int a = 0;
        #pragma unroll
        for (int e = 0; e < E_; e++) { offs[e] = a; a += cnt[e]; }
    }
}

// ------- bf16 MFMA 128x128 GEMM core (BK=32, global_load_lds, granule-swizzled) -------
// LDS is linear (gload_lds requires it); bank-conflict fix via pre-swizzled GLOBAL
// source granule + matching swizzled fragment-read granule (rule: both-sides-or-neither).
// granule swizzle s(row) = (row>>1)&3; source col granule = (lane&3)^((lane>>3)&3).
__device__ __forceinline__ void mfma_core(const unsigned short* __restrict__ A, int strideA,
        const int* __restrict__ gather, int m0, int M,
        const unsigned short* __restrict__ Bt, int strideB, int n0, int K, f32x4 acc[4][4]) {
    __shared__ unsigned short As[128 * 32];
    __shared__ unsigned short Bs[128 * 32];
    int t = threadIdx.x;
    int lane = t & 63, wid = t >> 6;
    int wm = (wid >> 1) * 64, wn = (wid & 1) * 64;
    int c15 = lane & 15;
    // fragment read: logical granule g = lane>>4, stored at g ^ ((row>>1)&3) = g ^ ((c15>>1)&3)
    int fk = (((lane >> 4) ^ ((c15 >> 1) & 3)) * 8);
    // staging: LDS row r0 granule (lane&3) gets global granule (lane&3)^((r0>>1)&3)
    int r0 = wid * 32 + (lane >> 2);
    int kc2 = (((lane & 3) ^ ((lane >> 3) & 3)) * 8);
    int ar0, ar1;
    {
        int mm0 = m0 + r0, mm1 = m0 + r0 + 16;
        if (gather) { ar0 = gather[mm0 < M ? mm0 : 0]; ar1 = gather[mm1 < M ? mm1 : 0]; }
        else        { ar0 = mm0; ar1 = mm1; }
    }
    const unsigned short* pA0 = A + (size_t)ar0 * strideA + kc2;
    const unsigned short* pA1 = A + (size_t)ar1 * strideA + kc2;
    const unsigned short* pB0 = Bt + (size_t)(n0 + r0) * strideB + kc2;
    const unsigned short* pB1 = Bt + (size_t)(n0 + r0 + 16) * strideB + kc2;
    unsigned short* lA0 = As + (wid * 2 + 0) * 512;   // 512 shorts = 1024 B
    unsigned short* lA1 = As + (wid * 2 + 1) * 512;
    unsigned short* lB0 = Bs + (wid * 2 + 0) * 512;
    unsigned short* lB1 = Bs + (wid * 2 + 1) * 512;
    for (int k0 = 0; k0 < K; k0 += 32) {
        __syncthreads();                 // previous-iter readers done
        gload16(pA0 + k0, lA0);
        gload16(pA1 + k0, lA1);
        gload16(pB0 + k0, lB0);
        gload16(pB1 + k0, lB1);
        __syncthreads();                 // drains vmcnt(0): LDS tiles ready
        bf16x8 af[4], bfr[4];
        #pragma unroll
        for (int i = 0; i < 4; i++) {
            af[i]  = *(const bf16x8*)(&As[(wm + c15 + i * 16) * 32 + fk]);
            bfr[i] = *(const bf16x8*)(&Bs[(wn + c15 + i * 16) * 32 + fk]);
        }
        #pragma unroll
        for (int mi = 0; mi < 4; mi++)
            #pragma unroll
            for (int ni = 0; ni < 4; ni++)
                acc[mi][ni] = __builtin_amdgcn_mfma_f32_16x16x32_bf16(af[mi], bfr[ni], acc[mi][ni], 0, 0, 0);
    }
}

// ---------------- MoE GEMM1: hid = gelu(h2[tok] @ we1[e] + be1[e]) ----------------
__global__ __launch_bounds__(256, 2) void k_moe1(const unsigned short* __restrict__ h2,
        const unsigned short* __restrict__ w1t, const float* __restrict__ be1,
        const int* __restrict__ cnt, const int* __restrict__ offs, const int* __restrict__ lst,
        unsigned short* __restrict__ hid) {
    // XCD-aware swizzle: grid (32,32,8), nwg=8192; XCD k owns expert k entirely
    int flat = blockIdx.x + (blockIdx.y << 5) + (blockIdx.z << 10);
    int sfl = ((flat & 7) << 10) + (flat >> 3);
    int bx = sfl & 31, by = (sfl >> 5) & 31, e = sfl >> 10;
    int M = cnt[e];
    int m0 = by * 128;
    if (m0 >= M) return;
    int n0 = bx * 128;
    f32x4 acc[4][4];
    #pragma unroll
    for (int i = 0; i < 4; i++)
        #pragma unroll
        for (int j = 0; j < 4; j++) { acc[i][j].x = 0.f; acc[i][j].y = 0.f; acc[i][j].z = 0.f; acc[i][j].w = 0.f; }
    mfma_core(h2, D_, lst + e * NTOK, m0, M, w1t + (size_t)e * F_ * D_, D_, n0, D_, acc);
    int lane = threadIdx.x & 63, w = threadIdx.x >> 6;
    int wm = (w >> 1) * 64, wn = (w & 1) * 64;
    int base = offs[e];
    const float* b1 = be1 + (size_t)e * F_;
    int c15 = lane & 15, quad = lane >> 4;
    #pragma unroll
    for (int mi = 0; mi < 4; mi++) {
        #pragma unroll
        for (int rr = 0; rr < 4; rr++) {
            int row = m0 + wm + mi * 16 + quad * 4 + rr;
            if (row < M) {
                size_t rb = (size_t)(base + row) * F_;
                #pragma unroll
                for (int ni = 0; ni < 4; ni++) {
                    int col = n0 + wn + ni * 16 + c15;
                    float xv = acc[mi][ni][rr] + b1[col];
                    float ge = 0.5f * xv * (1.0f + erf_fast(xv * 0.70710678118654752f));
                    hid[rb + col] = f2bf(ge);
                }
            }
        }
    }
}

// ------- MoE GEMM2, split-K=2: partial eo (bias added in k_final) -------
__global__ __launch_bounds__(256, 2) void k_moe2(const unsigned short* __restrict__ hid,
        const unsigned short* __restrict__ w2t,
        const int* __restrict__ cnt, const int* __restrict__ offs, float* __restrict__ eop) {
    // XCD-aware swizzle: grid (8,32,16), nwg=4096; XCD k owns expert k (both K halves)
    int flat = blockIdx.x + (blockIdx.y << 3) + (blockIdx.z << 8);
    int sfl = ((flat & 7) << 9) + (flat >> 3);
    int bx = sfl & 7, by = (sfl >> 3) & 31, ez = sfl >> 8;
    int e = ez >> 1, ks = ez & 1;          // expert, K half
    int M = cnt[e];
    int m0 = by * 128;
    if (m0 >= M) return;
    int n0 = bx * 128;
    int base = offs[e];
    f32x4 acc[4][4];
    #pragma unroll
    for (int i = 0; i < 4; i++)
        #pragma unroll
        for (int j = 0; j < 4; j++) { acc[i][j].x = 0.f; acc[i][j].y = 0.f; acc[i][j].z = 0.f; acc[i][j].w = 0.f; }
    mfma_core(hid + (size_t)base * F_ + ks * (F_ / 2), F_, nullptr, m0, M,
              w2t + (size_t)e * D_ * F_ + ks * (F_ / 2), F_, n0, F_ / 2, acc);
    float* dst = eop + (size_t)ks * 2 * NTOK * D_ + (size_t)base * D_;
    int lane = threadIdx.x & 63, w = threadIdx.x >> 6;
    int wm = (w >> 1) * 64, wn = (w & 1) * 64;
    int c15 = lane & 15, quad = lane >> 4;
    #pragma unroll
    for (int mi = 0; mi < 4; mi++) {
        #pragma unroll
        for (int rr = 0; rr < 4; rr++) {
            int row = m0 + wm + mi * 16 + quad * 4 + rr;
            if (row < M) {
                #pragma unroll
                for (int ni = 0; ni < 4; ni++) {
                    int col = n0 + wn + ni * 16 + c15;
                    dst[(size_t)row * D_ + col] = acc[mi][ni][rr];
                }
            }
        }
    }
}

// ---------------- final: merge moe partials, mix top-2, post-LN, residual ----------------
__global__ void k_final(const float* __restrict__ x2, const float* __restrict__ eop,
        const float* __restrict__ be2,
        const int* __restrict__ te, const int* __restrict__ ts, const float* __restrict__ tp,
        const int* __restrict__ offs, const float* __restrict__ png, const float* __restrict__ pnb,
        float* __restrict__ out) {
    int row = blockIdx.x, t = threadIdx.x;
    int e0 = te[row * 2], e1 = te[row * 2 + 1];
    size_t g0 = (size_t)(offs[e0] + ts[row * 2]);
    size_t g1 = (size_t)(offs[e1] + ts[row * 2 + 1]);
    float p0 = tp[row * 2], p1 = tp[row * 2 + 1];
    const size_t HALF = (size_t)2 * NTOK * D_;
    f32x4 a = *(const f32x4*)(eop + g0 * D_ + t * 4)
            + *(const f32x4*)(eop + HALF + g0 * D_ + t * 4)
            + *(const f32x4*)(be2 + (size_t)e0 * D_ + t * 4);
    f32x4 b = *(const f32x4*)(eop + g1 * D_ + t * 4)
            + *(const f32x4*)(eop + HALF + g1 * D_ + t * 4)
            + *(const f32x4*)(be2 + (size_t)e1 * D_ + t * 4);
    f32x4 mo = p0 * a + p1 * b;
    float s = mo.x + mo.y + mo.z + mo.w;
    float sq = mo.x * mo.x + mo.y * mo.y + mo.z * mo.z + mo.w * mo.w;
    blockreduce2(s, sq);
    float mean = s * (1.0f / D_), var = sq * (1.0f / D_) - mean * mean;
    float inv = rsqrtf(var + EPS_);
    f32x4 gv = *(const f32x4*)(png + t * 4);
    f32x4 bv = *(const f32x4*)(pnb + t * 4);
    f32x4 xv = *(const f32x4*)(x2 + (size_t)row * D_ + t * 4);
    f32x4 o;
    o.x = xv.x + (mo.x - mean) * inv * gv.x + bv.x;
    o.y = xv.y + (mo.y - mean) * inv * gv.y + bv.y;
    o.z = xv.z + (mo.z - mean) * inv * gv.z + bv.z;
    o.w = xv.w + (mo.w - mean) * inv * gv.w + bv.w;
    *(f32x4*)(out + (size_t)row * D_ + t * 4) = o;
}

extern "C" void kernel_launch(void* const* d_in, const int* in_sizes, int n_in,
                              void* d_out, int out_size, void* d_ws, size_t ws_size,
                              hipStream_t stream) {
    (void)in_sizes; (void)n_in; (void)out_size; (void)ws_size;
    const float* x    = (const float*)d_in[0];
    const float* ln1g = (const float*)d_in[2];
    const float* ln1b = (const float*)d_in[3];
    const float* wq   = (const float*)d_in[4];
    const float* bq   = (const float*)d_in[5];
    const float* wk   = (const float*)d_in[6];
    const float* bk   = (const float*)d_in[7];
    const float* wv   = (const float*)d_in[8];
    const float* bv   = (const float*)d_in[9];
    const float* wo   = (const float*)d_in[10];
    const float* bo   = (const float*)d_in[11];
    const float* ln2g = (const float*)d_in[12];
    const float* ln2b = (const float*)d_in[13];
    const float* gw   = (const float*)d_in[14];
    const float* gb   = (const float*)d_in[15];
    const float* we1  = (const float*)d_in[16];
    const float* be1  = (const float*)d_in[17];
    const float* we2  = (const float*)d_in[18];
    const float* be2  = (const float*)d_in[19];
    const float* png  = (const float*)d_in[20];
    const float* pnb  = (const float*)d_in[21];
    float* out = (float*)d_out;

    char* ws = (char*)d_ws;
    size_t off = 0;
    auto alloc = [&](size_t bytes) { void* p = ws + off; off += (bytes + 255) & ~(size_t)255; return p; };
    // --- region A: dead after k_proj_split; reused as eop (moe2 partials, 67.1MB < 83.9MB) ---
    unsigned short* h1h = (unsigned short*)alloc((size_t)NTOK * D_ * 2);
    unsigned short* h1l = (unsigned short*)alloc((size_t)NTOK * D_ * 2);
    unsigned short* Qhp = (unsigned short*)alloc((size_t)NTOK * D_ * 2);
    unsigned short* Qlp = (unsigned short*)alloc((size_t)NTOK * D_ * 2);
    unsigned short* Khp = (unsigned short*)alloc((size_t)NTOK * D_ * 2);
    unsigned short* Klp = (unsigned short*)alloc((size_t)NTOK * D_ * 2);
    unsigned short* Vhp = (unsigned short*)alloc((size_t)NTOK * D_ * 2);
    unsigned short* Vlp = (unsigned short*)alloc((size_t)NTOK * D_ * 2);
    unsigned short* atth = (unsigned short*)alloc((size_t)NTOK * D_ * 2);
    unsigned short* attl = (unsigned short*)alloc((size_t)NTOK * D_ * 2);
    float* x2  = (float*)alloc((size_t)NTOK * D_ * 4);
    unsigned short* h2  = (unsigned short*)alloc((size_t)NTOK * D_ * 2);
    unsigned short* w1t = (unsigned short*)alloc((size_t)E_ * D_ * F_ * 2);
    unsigned short* w2t = (unsigned short*)alloc((size_t)E_ * D_ * F_ * 2);
    unsigned short* hid = (unsigned short*)alloc((size_t)(2 * NTOK + 128) * F_ * 2);
    // --- region B: opart dead after k_attn2; reused as xp (proj partials, 33.6MB < 41.9MB) ---
    float* opart = (float*)alloc((size_t)64 * NSLOT * 64 * 64 * 4);   // 41.9 MB
    float* mlpart= (float*)alloc((size_t)64 * NSLOT * 128 * 4);       // 1.3 MB
    unsigned short* wsh = (unsigned short*)alloc((size_t)4 * D_ * D_ * 2);   // wq,wk,wv,wo ^T hi
    unsigned short* wsl = (unsigned short*)alloc((size_t)4 * D_ * D_ * 2);   // lo
    int* cnt   = (int*)alloc(256);
    int* offs  = (int*)alloc(256);
    int* lst   = (int*)alloc((size_t)E_ * NTOK * 4);
    int* te    = (int*)alloc((size_t)NTOK * 2 * 4);
    int* ts    = (int*)alloc((size_t)NTOK * 2 * 4);
    float* tp  = (float*)alloc((size_t)NTOK * 2 * 4);
    // aliases (stream-ordered liveness verified):
    float* xp  = opart;               // written by k_proj_split (after attn2), read by ln2_gate
    float* eop = (float*)h1h;         // written by k_moe2 (after proj), read by k_final

    k_zero<<<dim3(1), dim3(64), 0, stream>>>(cnt);
    k_tconv<<<dim3(F_ / 32, D_ / 32, E_), dim3(256), 0, stream>>>(we1, w1t, D_, F_);
    k_tconv<<<dim3(D_ / 32, F_ / 32, E_), dim3(256), 0, stream>>>(we2, w2t, F_, D_);
    k_tconv_split<<<dim3(D_ / 32, D_ / 32, 4), dim3(256), 0, stream>>>(wq, wk, wv, wo, wsh, wsl);
    k_ln1<<<dim3(NTOK), dim3(256), 0, stream>>>(x, ln1g, ln1b, h1h, h1l);
    k_qkv_split<<<dim3(D_ / 128, NTOK / 128, 3), dim3(256), 0, stream>>>(
        h1h, h1l, wsh, wsl, bq, bk, bv, Qhp, Qlp, Khp, Klp, Vhp, Vlp);
    k_attn1<<<dim3(4, T_ / 64, B_ * H_), dim3(256), 0, stream>>>(
        Qhp, Qlp, Khp, Klp, Vhp, Vlp, opart, mlpart);
    k_attn2<<<dim3(T_ / 64, B_ * H_), dim3(256), 0, stream>>>(opart, mlpart, atth, attl);
    k_proj_split<<<dim3(D_ / 128, NTOK / 128, 2), dim3(256), 0, stream>>>(
        atth, attl, wsh + (size_t)3 * D_ * D_, wsl + (size_t)3 * D_ * D_, xp);
    k_ln2_gate<<<dim3(NTOK), dim3(256), 0, stream>>>(
        xp, bo, x, x2, ln2g, ln2b, gw, gb, h2, cnt, lst, te, ts, tp);
    k_offs<<<dim3(1), dim3(64), 0, stream>>>(cnt, offs);
    k_moe1<<<dim3(F_ / 128, NTOK / 128, E_), dim3(256), 0, stream>>>(h2, w1t, be1, cnt, offs, lst, hid);
    k_moe2<<<dim3(D_ / 128, NTOK / 128, E_ * 2), dim3(256), 0, stream>>>(hid, w2t, cnt, offs, eop);
    k_final<<<dim3(NTOK), dim3(256), 0, stream>>>(x2, eop, be2, te, ts, tp, offs, png, pnb, out);
}

// Round 8
// 947.717 us; speedup vs baseline: 1.0395x; 1.0395x over previous
//
#include <hip/hip_runtime.h>
#include <hip/hip_bf16.h>
#include <math.h>

#define B_ 4
#define T_ 1024
#define D_ 1024
#define H_ 16
#define DH_ 64
#define F_ 4096
#define E_ 8
#define NTOK 4096
#define EPS_ 1e-5f

typedef float f32x4 __attribute__((ext_vector_type(4)));
typedef __bf16 bf16x8 __attribute__((ext_vector_type(8)));
typedef _Float16 f16x8 __attribute__((ext_vector_type(8)));

__device__ __forceinline__ unsigned short f2bf(float f) {
    unsigned u = __float_as_uint(f);
    u = u + 0x7fffu + ((u >> 16) & 1u);   // round-to-nearest-even
    return (unsigned short)(u >> 16);
}

// split fp32 into fp16 hi + fp16 lo where x ~= hi + lo/2048 (rel err ~2^-22)
__device__ __forceinline__ void splitf(float x, unsigned short& h, unsigned short& l) {
    _Float16 hf = (_Float16)x;
    _Float16 lf = (_Float16)((x - (float)hf) * 2048.0f);
    h = __builtin_bit_cast(unsigned short, hf);
    l = __builtin_bit_cast(unsigned short, lf);
}

// Abramowitz-Stegun 7.1.26 erf, |err| < 1.5e-7 (invisible after bf16 round)
__device__ __forceinline__ float erf_fast(float x) {
    float ax = fabsf(x);
    float t = 1.0f / fmaf(0.3275911f, ax, 1.0f);
    float y = t * fmaf(t, fmaf(t, fmaf(t, fmaf(t, 1.061405429f, -1.453152027f),
                  1.421413741f), -0.284496736f), 0.254829592f);
    float r = 1.0f - y * __expf(-ax * ax);
    return copysignf(r, x);
}

// async global->LDS, 16B per lane; LDS dest = wave-uniform base + lane*16
__device__ __forceinline__ void gload16(const unsigned short* g, unsigned short* l) {
    __builtin_amdgcn_global_load_lds(
        (const __attribute__((address_space(1))) unsigned int*)g,
        (__attribute__((address_space(3))) unsigned int*)l,
        16, 0, 0);
}

__device__ __forceinline__ void blockreduce2(float& s, float& sq) {
    #pragma unroll
    for (int o = 32; o > 0; o >>= 1) { s += __shfl_xor(s, o); sq += __shfl_xor(sq, o); }
    __shared__ float ls[4], lq[4];
    int w = threadIdx.x >> 6;
    if ((threadIdx.x & 63) == 0) { ls[w] = s; lq[w] = sq; }
    __syncthreads();
    s = ls[0] + ls[1] + ls[2] + ls[3];
    sq = lq[0] + lq[1] + lq[2] + lq[3];
}

// ---------------- zero routing counters ----------------
__global__ void k_zero(int* __restrict__ cnt) {
    if (threadIdx.x < E_) cnt[threadIdx.x] = 0;
}

// ------------- transpose fp32[e][R][C] -> bf16[e][C][R] -------------
__global__ void k_tconv(const float* __restrict__ in, unsigned short* __restrict__ out,
                        int R, int C) {
    __shared__ float tile[32][33];
    int e = blockIdx.z;
    const float* ine = in + (size_t)e * R * C;
    unsigned short* oute = out + (size_t)e * R * C;
    int tx = threadIdx.x & 31, ty = threadIdx.x >> 5;   // 32 x 8
    int c0 = blockIdx.x * 32, r0 = blockIdx.y * 32;
    #pragma unroll
    for (int j = 0; j < 32; j += 8)
        tile[ty + j][tx] = ine[(size_t)(r0 + ty + j) * C + c0 + tx];
    __syncthreads();
    #pragma unroll
    for (int j = 0; j < 32; j += 8)
        oute[(size_t)(c0 + ty + j) * R + r0 + tx] = f2bf(tile[tx][ty + j]);
}

// ------- transpose 4 attn weights fp32[D][D] -> split fp16 [z][N][K] -------
__global__ void k_tconv_split(const float* __restrict__ w0, const float* __restrict__ w1,
        const float* __restrict__ w2, const float* __restrict__ w3,
        unsigned short* __restrict__ ohi, unsigned short* __restrict__ olo) {
    __shared__ float tile[32][33];
    int z = blockIdx.z;
    const float* in = (z == 0) ? w0 : ((z == 1) ? w1 : ((z == 2) ? w2 : w3));
    unsigned short* oh = ohi + (size_t)z * D_ * D_;
    unsigned short* ol = olo + (size_t)z * D_ * D_;
    int tx = threadIdx.x & 31, ty = threadIdx.x >> 5;   // 32 x 8
    int c0 = blockIdx.x * 32, r0 = blockIdx.y * 32;
    #pragma unroll
    for (int j = 0; j < 32; j += 8)
        tile[ty + j][tx] = in[(size_t)(r0 + ty + j) * D_ + c0 + tx];
    __syncthreads();
    #pragma unroll
    for (int j = 0; j < 32; j += 8) {
        unsigned short h, l;
        splitf(tile[tx][ty + j], h, l);
        size_t o = (size_t)(c0 + ty + j) * D_ + r0 + tx;
        oh[o] = h; ol[o] = l;
    }
}

// ---------------- LayerNorm 1 (split fp16 out) ----------------
__global__ void k_ln1(const float* __restrict__ x, const float* __restrict__ g,
                      const float* __restrict__ b, unsigned short* __restrict__ hh,
                      unsigned short* __restrict__ hl) {
    int row = blockIdx.x, t = threadIdx.x;
    f32x4 v = *(const f32x4*)(x + (size_t)row * D_ + t * 4);
    float s = v.x + v.y + v.z + v.w;
    float sq = v.x * v.x + v.y * v.y + v.z * v.z + v.w * v.w;
    blockreduce2(s, sq);
    float mean = s * (1.0f / D_);
    float var = sq * (1.0f / D_) - mean * mean;
    float inv = rsqrtf(var + EPS_);
    f32x4 gv = *(const f32x4*)(g + t * 4);
    f32x4 bv = *(const f32x4*)(b + t * 4);
    ushort4 oh, ol;
    float o0 = (v.x - mean) * inv * gv.x + bv.x;
    float o1 = (v.y - mean) * inv * gv.y + bv.y;
    float o2 = (v.z - mean) * inv * gv.z + bv.z;
    float o3 = (v.w - mean) * inv * gv.w + bv.w;
    splitf(o0, oh.x, ol.x); splitf(o1, oh.y, ol.y);
    splitf(o2, oh.z, ol.z); splitf(o3, oh.w, ol.w);
    *(ushort4*)(hh + (size_t)row * D_ + t * 4) = oh;
    *(ushort4*)(hl + (size_t)row * D_ + t * 4) = ol;
}

// ------- split-fp16 3-pass MFMA 128x128 GEMM core (fp32-equivalent) -------
// result = acc1 + acc2 * (1/2048)
#define LDK2 40
__device__ __forceinline__ void mfma_split(const unsigned short* __restrict__ Ah,
        const unsigned short* __restrict__ Al, int strideA, int m0,
        const unsigned short* __restrict__ Bh, const unsigned short* __restrict__ Bl,
        int strideB, int n0, int K, f32x4 acc1[4][4], f32x4 acc2[4][4]) {
    __shared__ unsigned short AsH[128 * LDK2];
    __shared__ unsigned short AsL[128 * LDK2];
    __shared__ unsigned short BsH[128 * LDK2];
    __shared__ unsigned short BsL[128 * LDK2];
    int t = threadIdx.x;
    int lane = t & 63, w = t >> 6;
    int wm = (w >> 1) * 64, wn = (w & 1) * 64;
    int r = t >> 1, kc = (t & 1) * 16;
    const unsigned short* pAh = Ah + (size_t)(m0 + r) * strideA + kc;
    const unsigned short* pAl = Al + (size_t)(m0 + r) * strideA + kc;
    const unsigned short* pBh = Bh + (size_t)(n0 + r) * strideB + kc;
    const unsigned short* pBl = Bl + (size_t)(n0 + r) * strideB + kc;
    int c15 = lane & 15, fk = (lane >> 4) * 8;
    unsigned short* wAh = &AsH[r * LDK2 + kc];
    unsigned short* wAl = &AsL[r * LDK2 + kc];
    unsigned short* wBh = &BsH[r * LDK2 + kc];
    unsigned short* wBl = &BsL[r * LDK2 + kc];
    uint4 ah0 = *(const uint4*)(pAh);
    uint4 ah1 = *(const uint4*)(pAh + 8);
    uint4 al0 = *(const uint4*)(pAl);
    uint4 al1 = *(const uint4*)(pAl + 8);
    uint4 bh0 = *(const uint4*)(pBh);
    uint4 bh1 = *(const uint4*)(pBh + 8);
    uint4 bl0 = *(const uint4*)(pBl);
    uint4 bl1 = *(const uint4*)(pBl + 8);
    for (int k0 = 0; k0 < K; k0 += 32) {
        __syncthreads();
        *(uint4*)(wAh) = ah0; *(uint4*)(wAh + 8) = ah1;
        *(uint4*)(wAl) = al0; *(uint4*)(wAl + 8) = al1;
        *(uint4*)(wBh) = bh0; *(uint4*)(wBh + 8) = bh1;
        *(uint4*)(wBl) = bl0; *(uint4*)(wBl + 8) = bl1;
        __syncthreads();
        if (k0 + 32 < K) {
            ah0 = *(const uint4*)(pAh + k0 + 32);
            ah1 = *(const uint4*)(pAh + k0 + 40);
            al0 = *(const uint4*)(pAl + k0 + 32);
            al1 = *(const uint4*)(pAl + k0 + 40);
            bh0 = *(const uint4*)(pBh + k0 + 32);
            bh1 = *(const uint4*)(pBh + k0 + 40);
            bl0 = *(const uint4*)(pBl + k0 + 32);
            bl1 = *(const uint4*)(pBl + k0 + 40);
        }
        f16x8 bfh[4], bfl[4];
        #pragma unroll
        for (int i = 0; i < 4; i++) {
            bfh[i] = *(const f16x8*)(&BsH[(wn + c15 + i * 16) * LDK2 + fk]);
            bfl[i] = *(const f16x8*)(&BsL[(wn + c15 + i * 16) * LDK2 + fk]);
        }
        #pragma unroll
        for (int mi = 0; mi < 4; mi++) {
            f16x8 afh = *(const f16x8*)(&AsH[(wm + c15 + mi * 16) * LDK2 + fk]);
            f16x8 afl = *(const f16x8*)(&AsL[(wm + c15 + mi * 16) * LDK2 + fk]);
            #pragma unroll
            for (int ni = 0; ni < 4; ni++) {
                acc1[mi][ni] = __builtin_amdgcn_mfma_f32_16x16x32_f16(afh, bfh[ni], acc1[mi][ni], 0, 0, 0);
                acc2[mi][ni] = __builtin_amdgcn_mfma_f32_16x16x32_f16(afh, bfl[ni], acc2[mi][ni], 0, 0, 0);
                acc2[mi][ni] = __builtin_amdgcn_mfma_f32_16x16x32_f16(afl, bfh[ni], acc2[mi][ni], 0, 0, 0);
            }
        }
    }
}

// -------- QKV projection (split-fp16 MFMA), scatter to split-fp16 [B,H,T,DH] --------
__global__ __launch_bounds__(256, 2) void k_qkv_split(
        const unsigned short* __restrict__ h1h, const unsigned short* __restrict__ h1l,
        const unsigned short* __restrict__ wth, const unsigned short* __restrict__ wtl,
        const float* __restrict__ bq, const float* __restrict__ bk, const float* __restrict__ bv,
        unsigned short* __restrict__ Qh, unsigned short* __restrict__ Ql,
        unsigned short* __restrict__ Kh, unsigned short* __restrict__ Kl,
        unsigned short* __restrict__ Vh, unsigned short* __restrict__ Vl) {
    int which = blockIdx.z;
    const unsigned short* Bh = wth + (size_t)which * D_ * D_;
    const unsigned short* Bl = wtl + (size_t)which * D_ * D_;
    const float* bias = (which == 0) ? bq : ((which == 1) ? bk : bv);
    unsigned short* Oh = (which == 0) ? Qh : ((which == 1) ? Kh : Vh);
    unsigned short* Ol = (which == 0) ? Ql : ((which == 1) ? Kl : Vl);
    f32x4 a1[4][4], a2[4][4];
    #pragma unroll
    for (int i = 0; i < 4; i++)
        #pragma unroll
        for (int j = 0; j < 4; j++) {
            a1[i][j].x = 0.f; a1[i][j].y = 0.f; a1[i][j].z = 0.f; a1[i][j].w = 0.f;
            a2[i][j].x = 0.f; a2[i][j].y = 0.f; a2[i][j].z = 0.f; a2[i][j].w = 0.f;
        }
    int m0 = blockIdx.y * 128, n0 = blockIdx.x * 128;
    mfma_split(h1h, h1l, D_, m0, Bh, Bl, D_, n0, D_, a1, a2);
    int lane = threadIdx.x & 63, w = threadIdx.x >> 6;
    int wm = (w >> 1) * 64, wn = (w & 1) * 64;
    int c15 = lane & 15, quad = lane >> 4;
    #pragma unroll
    for (int mi = 0; mi < 4; mi++) {
        #pragma unroll
        for (int rr = 0; rr < 4; rr++) {
            int row = m0 + wm + mi * 16 + quad * 4 + rr;
            int bidx = row >> 10, tt = row & 1023;
            #pragma unroll
            for (int ni = 0; ni < 4; ni++) {
                int col = n0 + wn + ni * 16 + c15;
                float vv = a1[mi][ni][rr] + a2[mi][ni][rr] * (1.0f / 2048.0f) + bias[col];
                unsigned short hs, ls;
                splitf(vv, hs, ls);
                size_t idx = (((size_t)bidx * H_ + (col >> 6)) * T_ + tt) * DH_ + (col & 63);
                Oh[idx] = hs; Ol[idx] = ls;
            }
        }
    }
}

// -------- output projection, split-K=2: partial GEMM only (bias+residual in ln2_gate) --------
__global__ __launch_bounds__(256, 2) void k_proj_split(
        const unsigned short* __restrict__ ah, const unsigned short* __restrict__ al,
        const unsigned short* __restrict__ wh, const unsigned short* __restrict__ wl,
        float* __restrict__ xp) {
    int ks = blockIdx.z;              // K half: cols ks*512 .. +512
    f32x4 a1[4][4], a2[4][4];
    #pragma unroll
    for (int i = 0; i < 4; i++)
        #pragma unroll
        for (int j = 0; j < 4; j++) {
            a1[i][j].x = 0.f; a1[i][j].y = 0.f; a1[i][j].z = 0.f; a1[i][j].w = 0.f;
            a2[i][j].x = 0.f; a2[i][j].y = 0.f; a2[i][j].z = 0.f; a2[i][j].w = 0.f;
        }
    int m0 = blockIdx.y * 128, n0 = blockIdx.x * 128;
    mfma_split(ah + ks * 512, al + ks * 512, D_, m0,
               wh + ks * 512, wl + ks * 512, D_, n0, 512, a1, a2);
    float* dst = xp + (size_t)ks * NTOK * D_;
    int lane = threadIdx.x & 63, w = threadIdx.x >> 6;
    int wm = (w >> 1) * 64, wn = (w & 1) * 64;
    int c15 = lane & 15, quad = lane >> 4;
    #pragma unroll
    for (int mi = 0; mi < 4; mi++) {
        #pragma unroll
        for (int rr = 0; rr < 4; rr++) {
            int row = m0 + wm + mi * 16 + quad * 4 + rr;
            #pragma unroll
            for (int ni = 0; ni < 4; ni++) {
                int col = n0 + wn + ni * 16 + c15;
                dst[(size_t)row * D_ + col] = a1[mi][ni][rr] + a2[mi][ni][rr] * (1.0f / 2048.0f);
            }
        }
    }
}

// ---------------- flash attention pass 1: split-fp16 MFMA ----------------
#define NSLOT 40
__device__ __forceinline__ int slot_base(int qt) {
    const int base[16] = {0,1,2,3,4,6,8,10,12,15,18,21,24,28,32,36};
    return base[qt];
}
// swizzled byte offset into a [64][64] ushort LDS tile (row stride 128B)
__device__ __forceinline__ int swzb(int r, int cb) {
    return r * 128 + (cb ^ ((r & 7) << 4));
}
__global__ __launch_bounds__(256, 3) void k_attn1(
        const unsigned short* __restrict__ Qh, const unsigned short* __restrict__ Ql,
        const unsigned short* __restrict__ Kh, const unsigned short* __restrict__ Kl,
        const unsigned short* __restrict__ Vh, const unsigned short* __restrict__ Vl,
        float* __restrict__ opart, float* __restrict__ mlpart) {
    __shared__ unsigned short KsH[64 * 64], KsL[64 * 64];
    __shared__ unsigned short VtH[64 * 64], VtL[64 * 64];   // [d][k]
    __shared__ unsigned short PsH[64 * 64], PsL[64 * 64];   // [q][k]
    int sp = blockIdx.x, qt = blockIdx.y, bh = blockIdx.z;
    int lim = (qt + 1) * 64;
    int s0 = sp * 256;
    if (s0 >= lim) return;
    int ntile = min(4, (lim - s0) >> 6);
    int t = threadIdx.x;
    int lane = t & 63, w = t >> 6;
    int c15 = lane & 15, quad = lane >> 4;
    size_t bho = (size_t)bh * T_ * DH_;
    // ---- Q fragments directly to registers (reused across all k-tiles) ----
    f16x8 qfh[2], qfl[2];
    {
        const unsigned short* qb = Qh + bho + (size_t)(qt * 64 + w * 16 + c15) * DH_ + quad * 8;
        const unsigned short* ql2 = Ql + bho + (size_t)(qt * 64 + w * 16 + c15) * DH_ + quad * 8;
        qfh[0] = *(const f16x8*)(qb);
        qfh[1] = *(const f16x8*)(qb + 32);
        qfl[0] = *(const f16x8*)(ql2);
        qfl[1] = *(const f16x8*)(ql2 + 32);
    }
    int kr = t >> 2, kcb = (t & 3) * 32;            // K: row kr, byte cols kcb, kcb+16
    int vkp = (t & 31) * 2, vd0 = (t >> 5) * 8;     // V: k pair (vkp,vkp+1), d range vd0..+8
    f32x4 o1[4], o2[4];
    #pragma unroll
    for (int i = 0; i < 4; i++) {
        o1[i].x = 0.f; o1[i].y = 0.f; o1[i].z = 0.f; o1[i].w = 0.f;
        o2[i].x = 0.f; o2[i].y = 0.f; o2[i].z = 0.f; o2[i].w = 0.f;
    }
    float m[4] = {-1e30f, -1e30f, -1e30f, -1e30f};
    float l[4] = {0.f, 0.f, 0.f, 0.f};
    int qglob0 = qt * 64 + w * 16 + quad * 4;   // thread's first q row
    for (int kt = 0; kt < ntile; kt++) {
        int kbase = s0 + kt * 64;
        __syncthreads();   // prev-iter readers of Ks/Vt/Ps done
        // ---- stage K tile (in-phase: short live-range, no spill) ----
        {
            const unsigned short* sh = Kh + bho + (size_t)(kbase + kr) * DH_ + (kcb >> 1);
            const unsigned short* sl = Kl + bho + (size_t)(kbase + kr) * DH_ + (kcb >> 1);
            uint4 h0 = *(const uint4*)(sh);
            uint4 h1 = *(const uint4*)(sh + 8);
            uint4 l0 = *(const uint4*)(sl);
            uint4 l1 = *(const uint4*)(sl + 8);
            *(uint4*)((char*)KsH + swzb(kr, kcb))      = h0;
            *(uint4*)((char*)KsH + swzb(kr, kcb + 16)) = h1;
            *(uint4*)((char*)KsL + swzb(kr, kcb))      = l0;
            *(uint4*)((char*)KsL + swzb(kr, kcb + 16)) = l1;
        }
        // ---- stage V transposed [d][k], paired b32 writes (conflict-free) ----
        {
            const unsigned short* vh = Vh + bho + (size_t)(kbase + vkp) * DH_ + vd0;
            const unsigned short* vl = Vl + bho + (size_t)(kbase + vkp) * DH_ + vd0;
            uint4 vh0 = *(const uint4*)(vh);
            uint4 vh1 = *(const uint4*)(vh + DH_);
            uint4 vl0 = *(const uint4*)(vl);
            uint4 vl1 = *(const uint4*)(vl + DH_);
            unsigned short h0a[8], h1a[8], l0a[8], l1a[8];
            *(uint4*)h0a = vh0; *(uint4*)h1a = vh1;
            *(uint4*)l0a = vl0; *(uint4*)l1a = vl1;
            #pragma unroll
            for (int i = 0; i < 8; i++) {
                int d = vd0 + i;
                unsigned hv32 = (unsigned)h0a[i] | ((unsigned)h1a[i] << 16);
                unsigned lv32 = (unsigned)l0a[i] | ((unsigned)l1a[i] << 16);
                *(unsigned*)((char*)VtH + swzb(d, vkp * 2)) = hv32;
                *(unsigned*)((char*)VtL + swzb(d, vkp * 2)) = lv32;
            }
        }
        __syncthreads();
        // ---- QK^T: wave computes S[16q x 64k], split 3-pass ----
        f32x4 s1[4], s2[4];
        #pragma unroll
        for (int i = 0; i < 4; i++) {
            s1[i].x = 0.f; s1[i].y = 0.f; s1[i].z = 0.f; s1[i].w = 0.f;
            s2[i].x = 0.f; s2[i].y = 0.f; s2[i].z = 0.f; s2[i].w = 0.f;
        }
        #pragma unroll
        for (int kk = 0; kk < 2; kk++) {
            int cb = kk * 64 + quad * 16;
            f16x8 ah = qfh[kk];
            f16x8 al = qfl[kk];
            #pragma unroll
            for (int ni = 0; ni < 4; ni++) {
                f16x8 bh16 = *(const f16x8*)((char*)KsH + swzb(ni * 16 + c15, cb));
                f16x8 bl16 = *(const f16x8*)((char*)KsL + swzb(ni * 16 + c15, cb));
                s1[ni] = __builtin_amdgcn_mfma_f32_16x16x32_f16(ah, bh16, s1[ni], 0, 0, 0);
                s2[ni] = __builtin_amdgcn_mfma_f32_16x16x32_f16(ah, bl16, s2[ni], 0, 0, 0);
                s2[ni] = __builtin_amdgcn_mfma_f32_16x16x32_f16(al, bh16, s2[ni], 0, 0, 0);
            }
        }
        // ---- combine, scale, mask ----
        f32x4 p[4];
        #pragma unroll
        for (int ni = 0; ni < 4; ni++)
            p[ni] = s1[ni] * 0.125f + s2[ni] * 6.103515625e-5f;   // 0.125/2048
        #pragma unroll
        for (int ni = 0; ni < 4; ni++) {
            int kglob = kbase + c15 + 16 * ni;
            #pragma unroll
            for (int r = 0; r < 4; r++)
                p[ni][r] = (kglob <= qglob0 + r) ? p[ni][r] : -1e30f;
        }
        // ---- online softmax (per q row; row spans the 16 low lanes) ----
        float alpha[4];
        #pragma unroll
        for (int r = 0; r < 4; r++) {
            float rm = fmaxf(fmaxf(p[0][r], p[1][r]), fmaxf(p[2][r], p[3][r]));
            rm = fmaxf(rm, __shfl_xor(rm, 1));
            rm = fmaxf(rm, __shfl_xor(rm, 2));
            rm = fmaxf(rm, __shfl_xor(rm, 4));
            rm = fmaxf(rm, __shfl_xor(rm, 8));
            float mnew = fmaxf(m[r], rm);
            alpha[r] = __expf(m[r] - mnew);
            m[r] = mnew;
            float rs = 0.f;
            #pragma unroll
            for (int ni = 0; ni < 4; ni++) {
                float pv = (p[ni][r] > -1e29f) ? __expf(p[ni][r] - mnew) : 0.f;
                p[ni][r] = pv;
                rs += pv;
            }
            rs += __shfl_xor(rs, 1);
            rs += __shfl_xor(rs, 2);
            rs += __shfl_xor(rs, 4);
            rs += __shfl_xor(rs, 8);
            l[r] = l[r] * alpha[r] + rs;
        }
        #pragma unroll
        for (int ni = 0; ni < 4; ni++) {
            o1[ni].x *= alpha[0]; o1[ni].y *= alpha[1]; o1[ni].z *= alpha[2]; o1[ni].w *= alpha[3];
            o2[ni].x *= alpha[0]; o2[ni].y *= alpha[1]; o2[ni].z *= alpha[2]; o2[ni].w *= alpha[3];
        }
        // ---- write P split to LDS [q][k] ----
        #pragma unroll
        for (int ni = 0; ni < 4; ni++) {
            int cbyte = (c15 + 16 * ni) * 2;
            #pragma unroll
            for (int r = 0; r < 4; r++) {
                unsigned short hs, ls;
                splitf(p[ni][r], hs, ls);
                int row = w * 16 + quad * 4 + r;
                *(unsigned short*)((char*)PsH + swzb(row, cbyte)) = hs;
                *(unsigned short*)((char*)PsL + swzb(row, cbyte)) = ls;
            }
        }
        __syncthreads();
        // ---- PV: o[16q x 64d] += P @ V, split 3-pass ----
        #pragma unroll
        for (int kk = 0; kk < 2; kk++) {
            int cb = kk * 64 + quad * 16;
            f16x8 ph = *(const f16x8*)((char*)PsH + swzb(w * 16 + c15, cb));
            f16x8 pl = *(const f16x8*)((char*)PsL + swzb(w * 16 + c15, cb));
            #pragma unroll
            for (int ni = 0; ni < 4; ni++) {
                f16x8 vh16 = *(const f16x8*)((char*)VtH + swzb(ni * 16 + c15, cb));
                f16x8 vl16 = *(const f16x8*)((char*)VtL + swzb(ni * 16 + c15, cb));
                o1[ni] = __builtin_amdgcn_mfma_f32_16x16x32_f16(ph, vh16, o1[ni], 0, 0, 0);
                o2[ni] = __builtin_amdgcn_mfma_f32_16x16x32_f16(ph, vl16, o2[ni], 0, 0, 0);
                o2[ni] = __builtin_amdgcn_mfma_f32_16x16x32_f16(pl, vh16, o2[ni], 0, 0, 0);
            }
        }
    }
    // ---- write unnormalized partial + (m,l) ----
    int slot = bh * NSLOT + slot_base(qt) + sp;
    float* dst = opart + (size_t)slot * 64 * 64;
    #pragma unroll
    for (int ni = 0; ni < 4; ni++) {
        #pragma unroll
        for (int r = 0; r < 4; r++) {
            float val = o1[ni][r] + o2[ni][r] * (1.0f / 2048.0f);
            dst[(size_t)(w * 16 + quad * 4 + r) * 64 + c15 + 16 * ni] = val;
        }
    }
    if (c15 == 0) {
        #pragma unroll
        for (int r = 0; r < 4; r++) {
            int row = w * 16 + quad * 4 + r;
            mlpart[slot * 128 + row * 2 + 0] = m[r];
            mlpart[slot * 128 + row * 2 + 1] = l[r];
        }
    }
}

// ------- flash attention pass 2: merge partials, normalize, split-fp16 out -------
__global__ void k_attn2(const float* __restrict__ opart, const float* __restrict__ mlpart,
                        unsigned short* __restrict__ atth, unsigned short* __restrict__ attl) {
    int qt = blockIdx.x, bh = blockIdx.y;
    int b = bh >> 4, h = bh & 15;
    int nsp = (qt >> 2) + 1;
    int slot0 = bh * NSLOT + slot_base(qt);
    int tid = threadIdx.x;
    int q = tid >> 2, d0 = (tid & 3) * 16;
    float ms[4], ls[4];
    float mx = -1e30f;
    for (int s = 0; s < nsp; s++) {
        ms[s] = mlpart[(slot0 + s) * 128 + q * 2 + 0];
        ls[s] = mlpart[(slot0 + s) * 128 + q * 2 + 1];
        mx = fmaxf(mx, ms[s]);
    }
    float den = 0.f;
    f32x4 num[4];
    #pragma unroll
    for (int i = 0; i < 4; i++) { num[i].x = 0.f; num[i].y = 0.f; num[i].z = 0.f; num[i].w = 0.f; }
    for (int s = 0; s < nsp; s++) {
        float sc = __expf(ms[s] - mx);
        den += ls[s] * sc;
        const float* src = opart + ((size_t)(slot0 + s) * 64 + q) * 64 + d0;
        #pragma unroll
        for (int i = 0; i < 4; i++) num[i] += sc * *(const f32x4*)(src + i * 4);
    }
    float inv = 1.0f / den;
    size_t base = ((size_t)(b * T_ + qt * 64 + q)) * D_ + h * DH_ + d0;
    #pragma unroll
    for (int i = 0; i < 4; i++) {
        f32x4 v = num[i] * inv;
        ushort4 hh, ll;
        splitf(v.x, hh.x, ll.x); splitf(v.y, hh.y, ll.y);
        splitf(v.z, hh.z, ll.z); splitf(v.w, hh.w, ll.w);
        *(ushort4*)(atth + base + i * 4) = hh;
        *(ushort4*)(attl + base + i * 4) = ll;
    }
}

// ---- LN2 + gate: merge proj partials + bias + residual -> x2, then LN + top-2 ----
__global__ void k_ln2_gate(const float* __restrict__ xp, const float* __restrict__ bo,
        const float* __restrict__ xin, float* __restrict__ x2,
        const float* __restrict__ g, const float* __restrict__ bb,
        const float* __restrict__ gw, const float* __restrict__ gb,
        unsigned short* __restrict__ h2, int* __restrict__ cnt, int* __restrict__ lst,
        int* __restrict__ te, int* __restrict__ ts, float* __restrict__ tp) {
    int row = blockIdx.x, t = threadIdx.x;
    f32x4 v = *(const f32x4*)(xp + (size_t)row * D_ + t * 4)
            + *(const f32x4*)(xp + (size_t)NTOK * D_ + (size_t)row * D_ + t * 4)
            + *(const f32x4*)(bo + t * 4)
            + *(const f32x4*)(xin + (size_t)row * D_ + t * 4);
    *(f32x4*)(x2 + (size_t)row * D_ + t * 4) = v;
    float s = v.x + v.y + v.z + v.w;
    float sq = v.x * v.x + v.y * v.y + v.z * v.z + v.w * v.w;
    blockreduce2(s, sq);
    float mean = s * (1.0f / D_), var = sq * (1.0f / D_) - mean * mean;
    float inv = rsqrtf(var + EPS_);
    f32x4 gv = *(const f32x4*)(g + t * 4);
    f32x4 bv = *(const f32x4*)(bb + t * 4);
    float hv[4];
    #pragma unroll
    for (int i = 0; i < 4; i++) hv[i] = (v[i] - mean) * inv * gv[i] + bv[i];
    ushort4 hb;
    hb.x = f2bf(hv[0]); hb.y = f2bf(hv[1]); hb.z = f2bf(hv[2]); hb.w = f2bf(hv[3]);
    *(ushort4*)(&h2[(size_t)row * D_ + t * 4]) = hb;
    float lg[8];
    #pragma unroll
    for (int e2 = 0; e2 < 8; e2++) lg[e2] = 0.f;
    #pragma unroll
    for (int i = 0; i < 4; i++) {
        const float* gr = gw + (size_t)(t * 4 + i) * E_;
        f32x4 g0 = *(const f32x4*)(gr);
        f32x4 g1 = *(const f32x4*)(gr + 4);
        lg[0] = fmaf(hv[i], g0.x, lg[0]); lg[1] = fmaf(hv[i], g0.y, lg[1]);
        lg[2] = fmaf(hv[i], g0.z, lg[2]); lg[3] = fmaf(hv[i], g0.w, lg[3]);
        lg[4] = fmaf(hv[i], g1.x, lg[4]); lg[5] = fmaf(hv[i], g1.y, lg[5]);
        lg[6] = fmaf(hv[i], g1.z, lg[6]); lg[7] = fmaf(hv[i], g1.w, lg[7]);
    }
    #pragma unroll
    for (int o = 32; o > 0; o >>= 1) {
        #pragma unroll
        for (int e2 = 0; e2 < 8; e2++) lg[e2] += __shfl_xor(lg[e2], o);
    }
    __shared__ float lred[4][8];
    int w = t >> 6;
    if ((t & 63) == 0) {
        #pragma unroll
        for (int e2 = 0; e2 < 8; e2++) lred[w][e2] = lg[e2];
    }
    __syncthreads();
    if (t == 0) {
        float L[8];
        #pragma unroll
        for (int e2 = 0; e2 < 8; e2++)
            L[e2] = (lred[0][e2] + lred[1][e2] + lred[2][e2] + lred[3][e2] + gb[e2]) / 0.9f;
        int e0 = 0, e1 = -1; float v0 = L[0], v1 = -3e38f;
        #pragma unroll
        for (int e2 = 1; e2 < 8; e2++) {
            float xv = L[e2];
            if (xv > v0)      { v1 = v0; e1 = e0; v0 = xv; e0 = e2; }
            else if (xv > v1) { v1 = xv; e1 = e2; }
        }
        float ex = __expf(v1 - v0);
        float denom = 1.0f + ex;
        float p0 = 1.0f / denom, p1 = ex / denom;
        int s0 = atomicAdd(&cnt[e0], 1);
        int s1 = atomicAdd(&cnt[e1], 1);
        lst[e0 * NTOK + s0] = row;
        lst[e1 * NTOK + s1] = row;
        te[row * 2 + 0] = e0; te[row * 2 + 1] = e1;
        ts[row * 2 + 0] = s0; ts[row * 2 + 1] = s1;
        tp[row * 2 + 0] = p0; tp[row * 2 + 1] = p1;
    }
}

__global__ void k_offs(const int* __restrict__ cnt, int* __restrict__ offs) {
    if (threadIdx.x == 0 && blockIdx.x == 0) {
        int a = 0;
        #pragma unroll
        for (int e = 0; e < E_; e++) { offs[e] = a; a += cnt[e]; }
    }
}

// ------- bf16 MFMA 128x128 GEMM core (BK=32, global_load_lds, granule-swizzled) -------
// LDS is linear (gload_lds requires it); bank-conflict fix via pre-swizzled GLOBAL
// source granule + matching swizzled fragment-read granule (rule: both-sides-or-neither).
// granule swizzle s(row) = (row>>1)&3; source col granule = (lane&3)^((lane>>3)&3).
__device__ __forceinline__ void mfma_core(const unsigned short* __restrict__ A, int strideA,
        const int* __restrict__ gather, int m0, int M,
        const unsigned short* __restrict__ Bt, int strideB, int n0, int K, f32x4 acc[4][4]) {
    __shared__ unsigned short As[128 * 32];
    __shared__ unsigned short Bs[128 * 32];
    int t = threadIdx.x;
    int lane = t & 63, wid = t >> 6;
    int wm = (wid >> 1) * 64, wn = (wid & 1) * 64;
    int c15 = lane & 15;
    // fragment read: logical granule g = lane>>4, stored at g ^ ((row>>1)&3) = g ^ ((c15>>1)&3)
    int fk = (((lane >> 4) ^ ((c15 >> 1) & 3)) * 8);
    // staging: LDS row r0 granule (lane&3) gets global granule (lane&3)^((r0>>1)&3)
    int r0 = wid * 32 + (lane >> 2);
    int kc2 = (((lane & 3) ^ ((lane >> 3) & 3)) * 8);
    int ar0, ar1;
    {
        int mm0 = m0 + r0, mm1 = m0 + r0 + 16;
        if (gather) { ar0 = gather[mm0 < M ? mm0 : 0]; ar1 = gather[mm1 < M ? mm1 : 0]; }
        else        { ar0 = mm0; ar1 = mm1; }
    }
    const unsigned short* pA0 = A + (size_t)ar0 * strideA + kc2;
    const unsigned short* pA1 = A + (size_t)ar1 * strideA + kc2;
    const unsigned short* pB0 = Bt + (size_t)(n0 + r0) * strideB + kc2;
    const unsigned short* pB1 = Bt + (size_t)(n0 + r0 + 16) * strideB + kc2;
    unsigned short* lA0 = As + (wid * 2 + 0) * 512;   // 512 shorts = 1024 B
    unsigned short* lA1 = As + (wid * 2 + 1) * 512;
    unsigned short* lB0 = Bs + (wid * 2 + 0) * 512;
    unsigned short* lB1 = Bs + (wid * 2 + 1) * 512;
    for (int k0 = 0; k0 < K; k0 += 32) {
        __syncthreads();                 // previous-iter readers done
        gload16(pA0 + k0, lA0);
        gload16(pA1 + k0, lA1);
        gload16(pB0 + k0, lB0);
        gload16(pB1 + k0, lB1);
        __syncthreads();                 // drains vmcnt(0): LDS tiles ready
        bf16x8 af[4], bfr[4];
        #pragma unroll
        for (int i = 0; i < 4; i++) {
            af[i]  = *(const bf16x8*)(&As[(wm + c15 + i * 16) * 32 + fk]);
            bfr[i] = *(const bf16x8*)(&Bs[(wn + c15 + i * 16) * 32 + fk]);
        }
        #pragma unroll
        for (int mi = 0; mi < 4; mi++)
            #pragma unroll
            for (int ni = 0; ni < 4; ni++)
                acc[mi][ni] = __builtin_amdgcn_mfma_f32_16x16x32_bf16(af[mi], bfr[ni], acc[mi][ni], 0, 0, 0);
    }
}

// ---------------- MoE GEMM1: hid = gelu(h2[tok] @ we1[e] + be1[e]) ----------------
__global__ __launch_bounds__(256, 2) void k_moe1(const unsigned short* __restrict__ h2,
        const unsigned short* __restrict__ w1t, const float* __restrict__ be1,
        const int* __restrict__ cnt, const int* __restrict__ offs, const int* __restrict__ lst,
        unsigned short* __restrict__ hid) {
    // XCD-aware swizzle: grid (32,32,8), nwg=8192; XCD k owns expert k entirely
    int flat = blockIdx.x + (blockIdx.y << 5) + (blockIdx.z << 10);
    int sfl = ((flat & 7) << 10) + (flat >> 3);
    int bx = sfl & 31, by = (sfl >> 5) & 31, e = sfl >> 10;
    int M = cnt[e];
    int m0 = by * 128;
    if (m0 >= M) return;
    int n0 = bx * 128;
    f32x4 acc[4][4];
    #pragma unroll
    for (int i = 0; i < 4; i++)
        #pragma unroll
        for (int j = 0; j < 4; j++) { acc[i][j].x = 0.f; acc[i][j].y = 0.f; acc[i][j].z = 0.f; acc[i][j].w = 0.f; }
    mfma_core(h2, D_, lst + e * NTOK, m0, M, w1t + (size_t)e * F_ * D_, D_, n0, D_, acc);
    int lane = threadIdx.x & 63, w = threadIdx.x >> 6;
    int wm = (w >> 1) * 64, wn = (w & 1) * 64;
    int base = offs[e];
    const float* b1 = be1 + (size_t)e * F_;
    int c15 = lane & 15, quad = lane >> 4;
    #pragma unroll
    for (int mi = 0; mi < 4; mi++) {
        #pragma unroll
        for (int rr = 0; rr < 4; rr++) {
            int row = m0 + wm + mi * 16 + quad * 4 + rr;
            if (row < M) {
                size_t rb = (size_t)(base + row) * F_;
                #pragma unroll
                for (int ni = 0; ni < 4; ni++) {
                    int col = n0 + wn + ni * 16 + c15;
                    float xv = acc[mi][ni][rr] + b1[col];
                    float ge = 0.5f * xv * (1.0f + erf_fast(xv * 0.70710678118654752f));
                    hid[rb + col] = f2bf(ge);
                }
            }
        }
    }
}

// ------- MoE GEMM2, split-K=2: partial eo (bias added in k_final) -------
__global__ __launch_bounds__(256, 2) void k_moe2(const unsigned short* __restrict__ hid,
        const unsigned short* __restrict__ w2t,
        const int* __restrict__ cnt, const int* __restrict__ offs, float* __restrict__ eop) {
    // XCD-aware swizzle: grid (8,32,16), nwg=4096; XCD k owns expert k (both K halves)
    int flat = blockIdx.x + (blockIdx.y << 3) + (blockIdx.z << 8);
    int sfl = ((flat & 7) << 9) + (flat >> 3);
    int bx = sfl & 7, by = (sfl >> 3) & 31, ez = sfl >> 8;
    int e = ez >> 1, ks = ez & 1;          // expert, K half
    int M = cnt[e];
    int m0 = by * 128;
    if (m0 >= M) return;
    int n0 = bx * 128;
    int base = offs[e];
    f32x4 acc[4][4];
    #pragma unroll
    for (int i = 0; i < 4; i++)
        #pragma unroll
        for (int j = 0; j < 4; j++) { acc[i][j].x = 0.f; acc[i][j].y = 0.f; acc[i][j].z = 0.f; acc[i][j].w = 0.f; }
    mfma_core(hid + (size_t)base * F_ + ks * (F_ / 2), F_, nullptr, m0, M,
              w2t + (size_t)e * D_ * F_ + ks * (F_ / 2), F_, n0, F_ / 2, acc);
    float* dst = eop + (size_t)ks * 2 * NTOK * D_ + (size_t)base * D_;
    int lane = threadIdx.x & 63, w = threadIdx.x >> 6;
    int wm = (w >> 1) * 64, wn = (w & 1) * 64;
    int c15 = lane & 15, quad = lane >> 4;
    #pragma unroll
    for (int mi = 0; mi < 4; mi++) {
        #pragma unroll
        for (int rr = 0; rr < 4; rr++) {
            int row = m0 + wm + mi * 16 + quad * 4 + rr;
            if (row < M) {
                #pragma unroll
                for (int ni = 0; ni < 4; ni++) {
                    int col = n0 + wn + ni * 16 + c15;
                    dst[(size_t)row * D_ + col] = acc[mi][ni][rr];
                }
            }
        }
    }
}

// ---------------- final: merge moe partials, mix top-2, post-LN, residual ----------------
__global__ void k_final(const float* __restrict__ x2, const float* __restrict__ eop,
        const float* __restrict__ be2,
        const int* __restrict__ te, const int* __restrict__ ts, const float* __restrict__ tp,
        const int* __restrict__ offs, const float* __restrict__ png, const float* __restrict__ pnb,
        float* __restrict__ out) {
    int row = blockIdx.x, t = threadIdx.x;
    int e0 = te[row * 2], e1 = te[row * 2 + 1];
    size_t g0 = (size_t)(offs[e0] + ts[row * 2]);
    size_t g1 = (size_t)(offs[e1] + ts[row * 2 + 1]);
    float p0 = tp[row * 2], p1 = tp[row * 2 + 1];
    const size_t HALF = (size_t)2 * NTOK * D_;
    f32x4 a = *(const f32x4*)(eop + g0 * D_ + t * 4)
            + *(const f32x4*)(eop + HALF + g0 * D_ + t * 4)
            + *(const f32x4*)(be2 + (size_t)e0 * D_ + t * 4);
    f32x4 b = *(const f32x4*)(eop + g1 * D_ + t * 4)
            + *(const f32x4*)(eop + HALF + g1 * D_ + t * 4)
            + *(const f32x4*)(be2 + (size_t)e1 * D_ + t * 4);
    f32x4 mo = p0 * a + p1 * b;
    float s = mo.x + mo.y + mo.z + mo.w;
    float sq = mo.x * mo.x + mo.y * mo.y + mo.z * mo.z + mo.w * mo.w;
    blockreduce2(s, sq);
    float mean = s * (1.0f / D_), var = sq * (1.0f / D_) - mean * mean;
    float inv = rsqrtf(var + EPS_);
    f32x4 gv = *(const f32x4*)(png + t * 4);
    f32x4 bv = *(const f32x4*)(pnb + t * 4);
    f32x4 xv = *(const f32x4*)(x2 + (size_t)row * D_ + t * 4);
    f32x4 o;
    o.x = xv.x + (mo.x - mean) * inv * gv.x + bv.x;
    o.y = xv.y + (mo.y - mean) * inv * gv.y + bv.y;
    o.z = xv.z + (mo.z - mean) * inv * gv.z + bv.z;
    o.w = xv.w + (mo.w - mean) * inv * gv.w + bv.w;
    *(f32x4*)(out + (size_t)row * D_ + t * 4) = o;
}

extern "C" void kernel_launch(void* const* d_in, const int* in_sizes, int n_in,
                              void* d_out, int out_size, void* d_ws, size_t ws_size,
                              hipStream_t stream) {
    (void)in_sizes; (void)n_in; (void)out_size; (void)ws_size;
    const float* x    = (const float*)d_in[0];
    const float* ln1g = (const float*)d_in[2];
    const float* ln1b = (const float*)d_in[3];
    const float* wq   = (const float*)d_in[4];
    const float* bq   = (const float*)d_in[5];
    const float* wk   = (const float*)d_in[6];
    const float* bk   = (const float*)d_in[7];
    const float* wv   = (const float*)d_in[8];
    const float* bv   = (const float*)d_in[9];
    const float* wo   = (const float*)d_in[10];
    const float* bo   = (const float*)d_in[11];
    const float* ln2g = (const float*)d_in[12];
    const float* ln2b = (const float*)d_in[13];
    const float* gw   = (const float*)d_in[14];
    const float* gb   = (const float*)d_in[15];
    const float* we1  = (const float*)d_in[16];
    const float* be1  = (const float*)d_in[17];
    const float* we2  = (const float*)d_in[18];
    const float* be2  = (const float*)d_in[19];
    const float* png  = (const float*)d_in[20];
    const float* pnb  = (const float*)d_in[21];
    float* out = (float*)d_out;

    char* ws = (char*)d_ws;
    size_t off = 0;
    auto alloc = [&](size_t bytes) { void* p = ws + off; off += (bytes + 255) & ~(size_t)255; return p; };
    // --- region A: dead after k_proj_split; reused as eop (moe2 partials, 67.1MB < 83.9MB) ---
    unsigned short* h1h = (unsigned short*)alloc((size_t)NTOK * D_ * 2);
    unsigned short* h1l = (unsigned short*)alloc((size_t)NTOK * D_ * 2);
    unsigned short* Qhp = (unsigned short*)alloc((size_t)NTOK * D_ * 2);
    unsigned short* Qlp = (unsigned short*)alloc((size_t)NTOK * D_ * 2);
    unsigned short* Khp = (unsigned short*)alloc((size_t)NTOK * D_ * 2);
    unsigned short* Klp = (unsigned short*)alloc((size_t)NTOK * D_ * 2);
    unsigned short* Vhp = (unsigned short*)alloc((size_t)NTOK * D_ * 2);
    unsigned short* Vlp = (unsigned short*)alloc((size_t)NTOK * D_ * 2);
    unsigned short* atth = (unsigned short*)alloc((size_t)NTOK * D_ * 2);
    unsigned short* attl = (unsigned short*)alloc((size_t)NTOK * D_ * 2);
    float* x2  = (float*)alloc((size_t)NTOK * D_ * 4);
    unsigned short* h2  = (unsigned short*)alloc((size_t)NTOK * D_ * 2);
    unsigned short* w1t = (unsigned short*)alloc((size_t)E_ * D_ * F_ * 2);
    unsigned short* w2t = (unsigned short*)alloc((size_t)E_ * D_ * F_ * 2);
    unsigned short* hid = (unsigned short*)alloc((size_t)(2 * NTOK + 128) * F_ * 2);
    // --- region B: opart dead after k_attn2; reused as xp (proj partials, 33.6MB < 41.9MB) ---
    float* opart = (float*)alloc((size_t)64 * NSLOT * 64 * 64 * 4);   // 41.9 MB
    float* mlpart= (float*)alloc((size_t)64 * NSLOT * 128 * 4);       // 1.3 MB
    unsigned short* wsh = (unsigned short*)alloc((size_t)4 * D_ * D_ * 2);   // wq,wk,wv,wo ^T hi
    unsigned short* wsl = (unsigned short*)alloc((size_t)4 * D_ * D_ * 2);   // lo
    int* cnt   = (int*)alloc(256);
    int* offs  = (int*)alloc(256);
    int* lst   = (int*)alloc((size_t)E_ * NTOK * 4);
    int* te    = (int*)alloc((size_t)NTOK * 2 * 4);
    int* ts    = (int*)alloc((size_t)NTOK * 2 * 4);
    float* tp  = (float*)alloc((size_t)NTOK * 2 * 4);
    // aliases (stream-ordered liveness verified):
    float* xp  = opart;               // written by k_proj_split (after attn2), read by ln2_gate
    float* eop = (float*)h1h;         // written by k_moe2 (after proj), read by k_final

    k_zero<<<dim3(1), dim3(64), 0, stream>>>(cnt);
    k_tconv<<<dim3(F_ / 32, D_ / 32, E_), dim3(256), 0, stream>>>(we1, w1t, D_, F_);
    k_tconv<<<dim3(D_ / 32, F_ / 32, E_), dim3(256), 0, stream>>>(we2, w2t, F_, D_);
    k_tconv_split<<<dim3(D_ / 32, D_ / 32, 4), dim3(256), 0, stream>>>(wq, wk, wv, wo, wsh, wsl);
    k_ln1<<<dim3(NTOK), dim3(256), 0, stream>>>(x, ln1g, ln1b, h1h, h1l);
    k_qkv_split<<<dim3(D_ / 128, NTOK / 128, 3), dim3(256), 0, stream>>>(
        h1h, h1l, wsh, wsl, bq, bk, bv, Qhp, Qlp, Khp, Klp, Vhp, Vlp);
    k_attn1<<<dim3(4, T_ / 64, B_ * H_), dim3(256), 0, stream>>>(
        Qhp, Qlp, Khp, Klp, Vhp, Vlp, opart, mlpart);
    k_attn2<<<dim3(T_ / 64, B_ * H_), dim3(256), 0, stream>>>(opart, mlpart, atth, attl);
    k_proj_split<<<dim3(D_ / 128, NTOK / 128, 2), dim3(256), 0, stream>>>(
        atth, attl, wsh + (size_t)3 * D_ * D_, wsl + (size_t)3 * D_ * D_, xp);
    k_ln2_gate<<<dim3(NTOK), dim3(256), 0, stream>>>(
        xp, bo, x, x2, ln2g, ln2b, gw, gb, h2, cnt, lst, te, ts, tp);
    k_offs<<<dim3(1), dim3(64), 0, stream>>>(cnt, offs);
    k_moe1<<<dim3(F_ / 128, NTOK / 128, E_), dim3(256), 0, stream>>>(h2, w1t, be1, cnt, offs, lst, hid);
    k_moe2<<<dim3(D_ / 128, NTOK / 128, E_ * 2), dim3(256), 0, stream>>>(hid, w2t, cnt, offs, eop);
    k_final<<<dim3(NTOK), dim3(256), 0, stream>>>(x2, eop, be2, te, ts, tp, offs, png, pnb, out);
}